// Round 11
// baseline (301.543 us; speedup 1.0000x reference)
//
#include <hip/hip_runtime.h>

#define N_NODESC 50000
#define N_EDGESC 800000
#define XD 64
#define HIDD 128
#define CTXD 64
#define OUTD 64
#define NBINS 50176   // 196 * 256
#define NBKT 196      // coarse buckets (row >> 8)
#define NTILES 6250   // 800000 / 128

typedef __bf16 bf16x8 __attribute__((ext_vector_type(8)));
typedef float f32x4 __attribute__((ext_vector_type(4)));

__device__ __forceinline__ unsigned short f2bf(float x) {
    __bf16 b = (__bf16)x;
    return __builtin_bit_cast(unsigned short, b);
}
__device__ __forceinline__ unsigned int pack2(float lo, float hi) {
    return (unsigned int)f2bf(lo) | ((unsigned int)f2bf(hi) << 16);
}
__device__ __forceinline__ float bflo(unsigned v) {
    return __builtin_bit_cast(float, v << 16);
}
__device__ __forceinline__ float bfhi(unsigned v) {
    return __builtin_bit_cast(float, v & 0xFFFF0000u);
}

// lgkm-only barrier: leaves staged global loads (vmcnt) in flight
#define LBARRIER() asm volatile("s_waitcnt lgkmcnt(0)\ns_barrier" ::: "memory")

// ---------------------------------------------------------------------------
// Sort pass A: coarse 196-bucket histogram (LDS-aggregated, int4 reads)
// ---------------------------------------------------------------------------
__global__ __launch_bounds__(256) void bhist_k(const int* __restrict__ ei,
                                               int* __restrict__ gh)
{
    __shared__ int lh[NBKT];
    if (threadIdx.x < NBKT) lh[threadIdx.x] = 0;
    __syncthreads();
    int e = (blockIdx.x * 256 + threadIdx.x) * 4;
    int stride = gridDim.x * 256 * 4;
    for (; e < N_EDGESC; e += stride) {          // N_EDGESC % 4 == 0
        int4 r = *(const int4*)(ei + e);
        atomicAdd(&lh[r.x >> 8], 1);
        atomicAdd(&lh[r.y >> 8], 1);
        atomicAdd(&lh[r.z >> 8], 1);
        atomicAdd(&lh[r.w >> 8], 1);
    }
    __syncthreads();
    if (threadIdx.x < NBKT) atomicAdd(&gh[threadIdx.x], lh[threadIdx.x]);
}

// ---------------------------------------------------------------------------
// Sort pass B: scan 196 -> base + cursor
// ---------------------------------------------------------------------------
__global__ __launch_bounds__(256) void bscan_k(const int* __restrict__ gh,
                                               int* __restrict__ base,
                                               int* __restrict__ cursor)
{
    __shared__ int ps[256];
    int t = threadIdx.x;
    int v = (t < NBKT) ? gh[t] : 0;
    ps[t] = v;
    __syncthreads();
    for (int off = 1; off < 256; off <<= 1) {
        int u = (t >= off) ? ps[t - off] : 0;
        __syncthreads();
        ps[t] += u;
        __syncthreads();
    }
    if (t < NBKT) { base[t] = ps[t] - v; cursor[t] = ps[t] - v; }
}

// ---------------------------------------------------------------------------
// Sort pass C: block-aggregated reservation scatter (25k global atomics),
// int4 reads, 6272-edge (16B-aligned) chunks.
// ---------------------------------------------------------------------------
#define SC_BLOCKS 128
#define SC_CHUNK 6272   // multiple of 4; 128*6272 >= 800000

__global__ __launch_bounds__(1024) void bscat_k(const int* __restrict__ ei,
                                                int* __restrict__ cursor,
                                                int2* __restrict__ eg2)
{
    __shared__ int lh[NBKT], lbase[NBKT], lcur[NBKT];
    const int t = threadIdx.x;
    const int e0 = blockIdx.x * SC_CHUNK;
    const int e1 = min(e0 + SC_CHUNK, N_EDGESC);
    if (t < NBKT) lh[t] = 0;
    __syncthreads();
    for (int e = e0 + t * 4; e < e1; e += 4096) {
        if (e + 3 < e1) {
            int4 r = *(const int4*)(ei + e);
            atomicAdd(&lh[r.x >> 8], 1);
            atomicAdd(&lh[r.y >> 8], 1);
            atomicAdd(&lh[r.z >> 8], 1);
            atomicAdd(&lh[r.w >> 8], 1);
        } else {
            for (int i = e; i < e1; ++i) atomicAdd(&lh[ei[i] >> 8], 1);
        }
    }
    __syncthreads();
    if (t < NBKT) {
        lbase[t] = atomicAdd(&cursor[t], lh[t]);
        lcur[t] = 0;
    }
    __syncthreads();
    for (int e = e0 + t * 4; e < e1; e += 4096) {
        if (e + 3 < e1) {
            int4 r = *(const int4*)(ei + e);
            int4 c = *(const int4*)(ei + N_EDGESC + e);
            int b0 = r.x >> 8, b1 = r.y >> 8, b2 = r.z >> 8, b3 = r.w >> 8;
            int p0 = lbase[b0] + atomicAdd(&lcur[b0], 1);
            int p1 = lbase[b1] + atomicAdd(&lcur[b1], 1);
            int p2 = lbase[b2] + atomicAdd(&lcur[b2], 1);
            int p3 = lbase[b3] + atomicAdd(&lcur[b3], 1);
            eg2[p0] = make_int2(r.x, c.x);
            eg2[p1] = make_int2(r.y, c.y);
            eg2[p2] = make_int2(r.z, c.z);
            eg2[p3] = make_int2(r.w, c.w);
        } else {
            for (int i = e; i < e1; ++i) {
                int row = ei[i], col = ei[N_EDGESC + i];
                int b = row >> 8;
                int p = lbase[b] + atomicAdd(&lcur[b], 1);
                eg2[p] = make_int2(row, col);
            }
        }
    }
}

// ---------------------------------------------------------------------------
// Sort pass D: per-bucket (256-row) LDS counting sort -> row-sorted eg + cnt_f
// ---------------------------------------------------------------------------
__global__ __launch_bounds__(1024) void bsort_k(const int2* __restrict__ eg2,
                                                const int* __restrict__ base,
                                                const int* __restrict__ gh,
                                                int2* __restrict__ eg,
                                                float* __restrict__ cnt_f)
{
    __shared__ int h[256], pfx[256], cur[256];
    const int b = blockIdx.x;
    const int lo = base[b];
    const int n = gh[b];
    const int t = threadIdx.x;
    if (t < 256) h[t] = 0;
    __syncthreads();
    for (int i = t; i < n; i += 1024)
        atomicAdd(&h[eg2[lo + i].x & 255], 1);
    __syncthreads();
    if (t < 256) pfx[t] = h[t];
    __syncthreads();
    for (int off = 1; off < 256; off <<= 1) {
        int u = 0;
        if (t < 256 && t >= off) u = pfx[t - off];
        __syncthreads();
        if (t < 256) pfx[t] += u;
        __syncthreads();
    }
    if (t < 256) {
        cur[t] = pfx[t] - h[t];
        int row = b * 256 + t;
        if (row < N_NODESC) cnt_f[row] = (float)h[t];
    }
    __syncthreads();
    for (int i = t; i < n; i += 1024) {
        int2 rc = eg2[lo + i];
        int r = atomicAdd(&cur[rc.x & 255], 1);
        eg[lo + r] = rc;
    }
}

// ---------------------------------------------------------------------------
// Prep: bf16 weight transposes / combinations.
// ---------------------------------------------------------------------------
__global__ void prep_weights(const float* __restrict__ w1,
                             const float* __restrict__ l2m_w2,
                             const float* __restrict__ l1m_w2,
                             const float* __restrict__ l1a_w1,
                             const float* __restrict__ l1a_w2,
                             const float* __restrict__ l2a_w1,
                             const float* __restrict__ l2a_w2,
                             unsigned short* __restrict__ wp,
                             unsigned short* __restrict__ wq,
                             unsigned short* __restrict__ w2t1,
                             unsigned short* __restrict__ w2t2,
                             unsigned short* __restrict__ aw1t,
                             unsigned short* __restrict__ aw2t,
                             unsigned short* __restrict__ bw1t,
                             unsigned short* __restrict__ bw2t)
{
    int i0 = blockIdx.x * 256 + threadIdx.x;
    int stride = gridDim.x * 256;
    for (int idx = i0; idx < 128 * 224; idx += stride) {
        int n = idx / 224, k = idx - n * 224;
        float vp = 0.f, vq = 0.f;
        if (k < 64)        { vp = w1[k * 128 + n] - w1[(64 + k) * 128 + n];
                             vq = w1[(64 + k) * 128 + n]; }
        else if (k < 128)  { vp = w1[(130 + k - 64) * 128 + n]; }
        else if (k < 130)  { vp = -w1[(128 + (k - 128)) * 128 + n];
                             vq =  w1[(128 + (k - 128)) * 128 + n]; }
        wp[idx] = f2bf(vp);
        wq[idx] = f2bf(vq);
    }
    for (int idx = i0; idx < 64 * 128; idx += stride) {
        int n = idx >> 7, k = idx & 127;
        w2t1[idx] = f2bf(l1m_w2[k * 64 + n]);
        w2t2[idx] = f2bf(l2m_w2[k * 64 + n]);
        aw2t[idx] = f2bf(l1a_w2[k * 64 + n]);
        bw2t[idx] = f2bf(l2a_w2[k * 64 + n]);
    }
    for (int idx = i0; idx < 128 * 64; idx += stride) {
        int n = idx >> 6, k = idx & 63;
        aw1t[idx] = f2bf(l1a_w1[k * 128 + n]);
    }
    for (int idx = i0; idx < 128 * 128; idx += stride) {
        int n = idx >> 7, k = idx & 127;
        bw1t[idx] = f2bf(l2a_w1[k * 128 + n]);
    }
}

// ---------------------------------------------------------------------------
// node_u: U[n] = pos[n]@l1m_w1 (col side); Un[n] = b1 - U[n] (row side).
// ---------------------------------------------------------------------------
__global__ __launch_bounds__(256) void node_u(const float* __restrict__ pos,
                                              const float* __restrict__ w1,
                                              const float* __restrict__ b1,
                                              unsigned short* __restrict__ U,
                                              unsigned short* __restrict__ Un)
{
    int t = blockIdx.x * 256 + threadIdx.x;
    int n = t >> 2, part = t & 3;
    if (n >= N_NODESC) return;
    float2 p = *(const float2*)(pos + 2 * (size_t)n);
    const float4* wa = (const float4*)(w1 + part * 32);
    const float4* wb = (const float4*)(w1 + 128 + part * 32);
    const float4* bb = (const float4*)(b1 + part * 32);
    unsigned* Uw  = (unsigned*)U  + (size_t)n * 64 + part * 16;
    unsigned* Unw = (unsigned*)Un + (size_t)n * 64 + part * 16;
    #pragma unroll
    for (int q = 0; q < 8; ++q) {
        float4 a = wa[q], b = wb[q], f = bb[q];
        float h0 = fmaf(p.x, a.x, p.y * b.x);
        float h1 = fmaf(p.x, a.y, p.y * b.y);
        float h2 = fmaf(p.x, a.z, p.y * b.z);
        float h3 = fmaf(p.x, a.w, p.y * b.w);
        Uw[2 * q]      = pack2(h0, h1);
        Uw[2 * q + 1]  = pack2(h2, h3);
        Unw[2 * q]     = pack2(f.x - h0, f.y - h1);
        Unw[2 * q + 1] = pack2(f.z - h2, f.w - h3);
    }
}

// ---------------------------------------------------------------------------
// edge_mlp: persistent 512 blocks (2/CU), INTERLEAVED tile mapping: XCD k owns
// tiles [tk,tk1); its 64 blocks process them strided by 64, so resident blocks
// always cover ~64 consecutive tiles (sliding window -> atomic lines L2-hot),
// with no scheduling tail. dbuf H, lgkm-only barriers, register-staged gather
// pipeline, run-merged atomic segment-sum.
// ---------------------------------------------------------------------------
#define EM_LDS (2 * 128 * 136 * 2 + 2 * 128 * 4)
#define EM_GRID 512

#define TILE_IDX(S) ((size_t)(tk + (S) * 64 + j) * 128)

#define TILE_BODY(BB, SS)                                                      \
  {                                                                            \
    unsigned short* Hc = (BB) ? H1 : H0;                                       \
    int* rowsc = (BB) ? rows1 : rows0;                                         \
    const int rcur = e2[BB].x;                                                 \
    if ((SS) + 1 < ns) {                                                       \
        const uint4* pr = (const uint4*)(Rr + (size_t)e2[(BB)^1].x * 128 + part * 32); \
        const uint4* pc = (const uint4*)(Cc + (size_t)e2[(BB)^1].y * 128 + part * 32); \
        _Pragma("unroll")                                                      \
        for (int qq = 0; qq < 4; ++qq) { sR[(BB)^1][qq] = pr[qq]; sC[(BB)^1][qq] = pc[qq]; } \
    }                                                                          \
    if ((SS) + 2 < ns) e2[BB] = eg[TILE_IDX((SS) + 2) + el];                   \
    if (part == 0) rowsc[el] = rcur;                                           \
    {                                                                          \
        uint4* Hw = (uint4*)((unsigned*)Hc + el * 68 + part * 16);             \
        _Pragma("unroll")                                                      \
        for (int qq = 0; qq < 4; ++qq) {                                       \
            uint4 pv = sR[BB][qq], qv = sC[BB][qq];                            \
            unsigned w0 = pack2(fmaxf(bflo(pv.x) + bflo(qv.x), 0.f),           \
                                fmaxf(bfhi(pv.x) + bfhi(qv.x), 0.f));          \
            unsigned w1v = pack2(fmaxf(bflo(pv.y) + bflo(qv.y), 0.f),          \
                                 fmaxf(bfhi(pv.y) + bfhi(qv.y), 0.f));         \
            unsigned w2v = pack2(fmaxf(bflo(pv.z) + bflo(qv.z), 0.f),          \
                                 fmaxf(bfhi(pv.z) + bfhi(qv.z), 0.f));         \
            unsigned w3v = pack2(fmaxf(bflo(pv.w) + bflo(qv.w), 0.f),          \
                                 fmaxf(bfhi(pv.w) + bfhi(qv.w), 0.f));         \
            Hw[qq] = make_uint4(w0, w1v, w2v, w3v);                            \
        }                                                                      \
    }                                                                          \
    LBARRIER();                                                                \
    f32x4 acc[4];                                                              \
    _Pragma("unroll")                                                          \
    for (int m = 0; m < 4; ++m) acc[m] = (f32x4){0.f, 0.f, 0.f, 0.f};          \
    _Pragma("unroll")                                                          \
    for (int k = 0; k < 4; ++k) {                                              \
        int kb = k * 32 + l4 * 8;                                              \
        _Pragma("unroll")                                                      \
        for (int m = 0; m < 4; ++m) {                                          \
            bf16x8 a = *(const bf16x8*)(Hc + (mh + m * 16 + l15) * 136 + kb);  \
            acc[m] = __builtin_amdgcn_mfma_f32_16x16x32_bf16(a, bfrag[k], acc[m], 0, 0, 0); \
        }                                                                      \
    }                                                                          \
    LBARRIER();                                                                \
    float* S = (float*)Hc;                                                     \
    _Pragma("unroll")                                                          \
    for (int m = 0; m < 4; ++m) {                                              \
        int rb = mh + m * 16 + l4 * 4;                                         \
        _Pragma("unroll")                                                      \
        for (int r = 0; r < 4; ++r)                                            \
            S[(rb + r) * 68 + nw + l15] = acc[m][r];                           \
    }                                                                          \
    LBARRIER();                                                                \
    {                                                                          \
        const int c = lane;                                                    \
        const int e0g = wave * 16;                                             \
        float sv[16]; int rw[16];                                              \
        _Pragma("unroll")                                                      \
        for (int r = 0; r < 16; ++r) sv[r] = S[(e0g + r) * 68 + c];            \
        _Pragma("unroll")                                                      \
        for (int r = 0; r < 16; ++r)                                           \
            rw[r] = __builtin_amdgcn_readfirstlane(rowsc[e0g + r]);            \
        int cur = rw[0]; float v = sv[0];                                      \
        _Pragma("unroll")                                                      \
        for (int r = 1; r < 16; ++r) {                                         \
            if (rw[r] == cur) { v += sv[r]; }                                  \
            else { unsafeAtomicAdd(sumout + (size_t)cur * 64 + c, v); cur = rw[r]; v = sv[r]; } \
        }                                                                      \
        unsafeAtomicAdd(sumout + (size_t)cur * 64 + c, v);                     \
    }                                                                          \
  }

__global__ __launch_bounds__(512, 4) void edge_mlp(
    const int2* __restrict__ eg,
    const unsigned short* __restrict__ Rr,   // row-side [N][128] (bias folded)
    const unsigned short* __restrict__ Cc,   // col-side [N][128]
    const unsigned short* __restrict__ w2t,  // [64][128]
    float* __restrict__ sumout)              // [N][64]
{
    extern __shared__ char smem[];
    unsigned short* H0 = (unsigned short*)smem;
    unsigned short* H1 = H0 + 128 * 136;
    int* rows0 = (int*)(smem + 2 * 128 * 136 * 2);
    int* rows1 = rows0 + 128;

    const int tid = threadIdx.x;
    const int el = tid >> 2, part = tid & 3;
    const int lane = tid & 63, l15 = lane & 15, l4 = lane >> 4;
    const int wave = tid >> 6;
    const int mh = (wave >> 2) * 64;
    const int nw = (wave & 3) * 16;

    // interleaved persistent mapping (see header comment)
    const int kx = blockIdx.x & 7;        // XCD (dispatch round-robin)
    const int j  = blockIdx.x >> 3;       // block lane within XCD [0,64)
    const int tk  = (NTILES * kx) >> 3;
    const int tk1 = (NTILES * (kx + 1)) >> 3;
    const int ns = (tk1 - tk - j + 63) >> 6;   // tiles for this block

    bf16x8 bfrag[4];
    #pragma unroll
    for (int k = 0; k < 4; ++k)
        bfrag[k] = *(const bf16x8*)(w2t + (nw + l15) * 128 + k * 32 + l4 * 8);

    uint4 sR[2][4], sC[2][4];
    int2 e2[2];

    e2[0] = eg[TILE_IDX(0) + el];
    if (ns > 1) e2[1] = eg[TILE_IDX(1) + el];
    {
        const uint4* pr = (const uint4*)(Rr + (size_t)e2[0].x * 128 + part * 32);
        const uint4* pc = (const uint4*)(Cc + (size_t)e2[0].y * 128 + part * 32);
        #pragma unroll
        for (int qq = 0; qq < 4; ++qq) { sR[0][qq] = pr[qq]; sC[0][qq] = pc[qq]; }
    }

    for (int s = 0; s < ns; s += 2) {
        TILE_BODY(0, s)
        if (s + 1 < ns) TILE_BODY(1, s + 1)
    }
}

// ---------------------------------------------------------------------------
// ctx_pq (fused): phase 1 computes ctx = MLP(mean(m1)+l1m_b2) in-register;
// phase 2 builds the PQ A-tile [128][248]bf16 directly in LDS and computes
// P/Q with B read from L2-hot global. LDS 62 KB -> 2 blocks/CU.
// ---------------------------------------------------------------------------
#define CP_LDS (128 * 248 * 2)   // 63488 B; phase-1 A1(18432)+H1(34816) fit inside

__global__ __launch_bounds__(512, 4) void ctx_pq(
    const float* __restrict__ sum1, const float* __restrict__ cnt,
    const float* __restrict__ mb2,
    const unsigned short* __restrict__ aw1t, const float* __restrict__ ab1,
    const unsigned short* __restrict__ aw2t, const float* __restrict__ ab2,
    const float* __restrict__ x, const float* __restrict__ pos,
    const unsigned short* __restrict__ wp, const unsigned short* __restrict__ wq,
    const float* __restrict__ b1,
    unsigned short* __restrict__ Pp, unsigned short* __restrict__ Qq)
{
    extern __shared__ char smem[];
    unsigned short* A1 = (unsigned short*)smem;            // [128][72]
    unsigned short* H1 = (unsigned short*)(smem + 18432);  // [128][136]
    const int tid = threadIdx.x;
    const int nb = blockIdx.x * 128;
    const int nl = tid >> 2, part = tid & 3;
    const int lane = tid & 63, l15 = lane & 15, l4 = lane >> 4;
    const int wave = tid >> 6;
    const int mh = (wave >> 2) * 64;

    int n = nb + nl; if (n >= N_NODESC) n = N_NODESC - 1;

    float4 xr[4];
    {
        const float4* xs = (const float4*)(x + (size_t)n * XD + part * 16);
        #pragma unroll
        for (int q = 0; q < 4; ++q) xr[q] = xs[q];
    }
    float2 posr = *(const float2*)(pos + 2 * (size_t)n);

    // phase 1a: A1 = bf16(mean(sum1) + mb2)
    {
        float inv = 1.0f / fmaxf(cnt[n], 1.0f);
        const float4* s = (const float4*)(sum1 + (size_t)n * CTXD + part * 16);
        const float4* m = (const float4*)(mb2 + part * 16);
        unsigned* Aw = (unsigned*)A1 + nl * 36 + part * 8;
        #pragma unroll
        for (int q = 0; q < 4; ++q) {
            float4 v = s[q]; float4 b = m[q];
            Aw[2 * q]     = pack2(fmaf(v.x, inv, b.x), fmaf(v.y, inv, b.y));
            Aw[2 * q + 1] = pack2(fmaf(v.z, inv, b.z), fmaf(v.w, inv, b.w));
        }
    }
    __syncthreads();

    // phase 1b: hidden = relu(A1 @ aw1t + ab1) -> H1
    const int nq = (wave & 3) * 32;
    {
        f32x4 acc1[4][2];
        #pragma unroll
        for (int m = 0; m < 4; ++m)
            #pragma unroll
            for (int nn = 0; nn < 2; ++nn) acc1[m][nn] = (f32x4){0.f, 0.f, 0.f, 0.f};
        #pragma unroll
        for (int kc = 0; kc < 2; ++kc) {
            int kb = kc * 32 + l4 * 8;
            bf16x8 b0 = *(const bf16x8*)(aw1t + (nq + l15) * 64 + kb);
            bf16x8 b1v = *(const bf16x8*)(aw1t + (nq + 16 + l15) * 64 + kb);
            #pragma unroll
            for (int m = 0; m < 4; ++m) {
                bf16x8 a = *(const bf16x8*)(A1 + (mh + m * 16 + l15) * 72 + kb);
                acc1[m][0] = __builtin_amdgcn_mfma_f32_16x16x32_bf16(a, b0, acc1[m][0], 0, 0, 0);
                acc1[m][1] = __builtin_amdgcn_mfma_f32_16x16x32_bf16(a, b1v, acc1[m][1], 0, 0, 0);
            }
        }
        float bv0 = ab1[nq + l15], bv1 = ab1[nq + 16 + l15];
        #pragma unroll
        for (int m = 0; m < 4; ++m) {
            int rb = mh + m * 16 + l4 * 4;
            #pragma unroll
            for (int nn = 0; nn < 2; ++nn) {
                float bv = nn ? bv1 : bv0;
                int col = nq + nn * 16 + l15;
                #pragma unroll
                for (int r = 0; r < 4; ++r)
                    H1[(rb + r) * 136 + col] = f2bf(fmaxf(acc1[m][nn][r] + bv, 0.f));
            }
        }
    }
    __syncthreads();

    // phase 1c: ctx = H1 @ aw2t + ab2 (kept in acc2 registers)
    const int nw = (wave & 3) * 16;
    f32x4 acc2[4];
    #pragma unroll
    for (int m = 0; m < 4; ++m) acc2[m] = (f32x4){0.f, 0.f, 0.f, 0.f};
    #pragma unroll
    for (int kc = 0; kc < 4; ++kc) {
        int kb = kc * 32 + l4 * 8;
        bf16x8 b = *(const bf16x8*)(aw2t + (nw + l15) * 128 + kb);
        #pragma unroll
        for (int m = 0; m < 4; ++m) {
            bf16x8 a = *(const bf16x8*)(H1 + (mh + m * 16 + l15) * 136 + kb);
            acc2[m] = __builtin_amdgcn_mfma_f32_16x16x32_bf16(a, b, acc2[m], 0, 0, 0);
        }
    }
    float cb2 = ab2[nw + l15];
    __syncthreads();   // all A1/H1 reads complete before A2 overwrites

    // phase 2a: build A2 [128 nodes][248 shorts]: x | ctx | pos | zeros
    {
        unsigned* Aw = (unsigned*)smem + nl * 124;
        #pragma unroll
        for (int q = 0; q < 4; ++q) {
            Aw[part * 8 + 2 * q]     = pack2(xr[q].x, xr[q].y);
            Aw[part * 8 + 2 * q + 1] = pack2(xr[q].z, xr[q].w);
        }
        if (part < 3) {
            #pragma unroll
            for (int z = 0; z < 15; ++z) Aw[65 + part * 15 + z] = 0u;
        } else {
            #pragma unroll
            for (int z = 0; z < 14; ++z) Aw[110 + z] = 0u;
            Aw[64] = pack2(posr.x, posr.y);   // feats 128,129
        }
    }
    {   // ctx (bf16) into feats 64..127 straight from accumulators
        unsigned short* A2s = (unsigned short*)smem;
        #pragma unroll
        for (int m = 0; m < 4; ++m) {
            int rb = mh + m * 16 + l4 * 4;
            #pragma unroll
            for (int r = 0; r < 4; ++r)
                A2s[(rb + r) * 248 + 64 + nw + l15] = f2bf(acc2[m][r] + cb2);
        }
    }
    __syncthreads();

    // phase 2b: P/Q MFMAs; B operands from L2-hot global
    const int nq2 = wave & 3;
    f32x4 acc[4][4];
    #pragma unroll
    for (int m = 0; m < 4; ++m)
        #pragma unroll
        for (int nn = 0; nn < 4; ++nn) acc[m][nn] = (f32x4){0.f, 0.f, 0.f, 0.f};

    if (nq2 < 2) {
        const int cb = nq2 * 64;
        #pragma unroll
        for (int kc = 0; kc < 7; ++kc) {
            int ks = kc * 32 + l4 * 8;        // short offset within 224-row
            int ko = ks * 2;                  // byte offset within 496-stride
            bf16x8 b0 = *(const bf16x8*)(wp + (cb + l15) * 224 + ks);
            bf16x8 b1v = *(const bf16x8*)(wp + (cb + 16 + l15) * 224 + ks);
            bf16x8 b2v = *(const bf16x8*)(wp + (cb + 32 + l15) * 224 + ks);
            bf16x8 b3v = *(const bf16x8*)(wp + (cb + 48 + l15) * 224 + ks);
            #pragma unroll
            for (int m = 0; m < 4; ++m) {
                bf16x8 a = *(const bf16x8*)(smem + (mh + m * 16 + l15) * 496 + ko);
                acc[m][0] = __builtin_amdgcn_mfma_f32_16x16x32_bf16(a, b0, acc[m][0], 0, 0, 0);
                acc[m][1] = __builtin_amdgcn_mfma_f32_16x16x32_bf16(a, b1v, acc[m][1], 0, 0, 0);
                acc[m][2] = __builtin_amdgcn_mfma_f32_16x16x32_bf16(a, b2v, acc[m][2], 0, 0, 0);
                acc[m][3] = __builtin_amdgcn_mfma_f32_16x16x32_bf16(a, b3v, acc[m][3], 0, 0, 0);
            }
        }
        #pragma unroll
        for (int nn = 0; nn < 4; ++nn) {
            int col = cb + nn * 16 + l15;
            float bb = b1[col];
            #pragma unroll
            for (int m = 0; m < 4; ++m) {
                int rb = mh + m * 16 + l4 * 4;
                #pragma unroll
                for (int r = 0; r < 4; ++r) {
                    int node = nb + rb + r;
                    if (node < N_NODESC)
                        Pp[(size_t)node * 128 + col] = f2bf(acc[m][nn][r] + bb);
                }
            }
        }
    } else {
        const int cb = (nq2 - 2) * 64;
        const int kcs[3] = {0, 1, 4};
        #pragma unroll
        for (int tk2 = 0; tk2 < 3; ++tk2) {
            int kc = kcs[tk2];
            int ks = kc * 32 + l4 * 8;
            bf16x8 b0 = *(const bf16x8*)(wq + (cb + l15) * 224 + ks);
            bf16x8 b1v = *(const bf16x8*)(wq + (cb + 16 + l15) * 224 + ks);
            bf16x8 b2v = *(const bf16x8*)(wq + (cb + 32 + l15) * 224 + ks);
            bf16x8 b3v = *(const bf16x8*)(wq + (cb + 48 + l15) * 224 + ks);
            #pragma unroll
            for (int m = 0; m < 4; ++m) {
                bf16x8 a = *(const bf16x8*)(smem + (mh + m * 16 + l15) * 496 + ks * 2);
                acc[m][0] = __builtin_amdgcn_mfma_f32_16x16x32_bf16(a, b0, acc[m][0], 0, 0, 0);
                acc[m][1] = __builtin_amdgcn_mfma_f32_16x16x32_bf16(a, b1v, acc[m][1], 0, 0, 0);
                acc[m][2] = __builtin_amdgcn_mfma_f32_16x16x32_bf16(a, b2v, acc[m][2], 0, 0, 0);
                acc[m][3] = __builtin_amdgcn_mfma_f32_16x16x32_bf16(a, b3v, acc[m][3], 0, 0, 0);
            }
        }
        #pragma unroll
        for (int nn = 0; nn < 4; ++nn) {
            int col = cb + nn * 16 + l15;
            #pragma unroll
            for (int m = 0; m < 4; ++m) {
                int rb = mh + m * 16 + l4 * 4;
                #pragma unroll
                for (int r = 0; r < 4; ++r) {
                    int node = nb + rb + r;
                    if (node < N_NODESC)
                        Qq[(size_t)node * 128 + col] = f2bf(acc[m][nn][r]);
                }
            }
        }
    }
}

// ---------------------------------------------------------------------------
// out = MLP([x, mean(m2)+l2m_b2]) (128 -> 128 -> 64), MFMA
// ---------------------------------------------------------------------------
__global__ __launch_bounds__(512) void out_mfma(
    const float* __restrict__ x, const float* __restrict__ sum2,
    const float* __restrict__ cnt, const float* __restrict__ mb2,
    const unsigned short* __restrict__ bw1t, const float* __restrict__ ab1,
    const unsigned short* __restrict__ bw2t, const float* __restrict__ ab2,
    float* __restrict__ out)
{
    extern __shared__ unsigned short sm[];
    unsigned short* A = sm;              // [128][136]
    unsigned short* H = sm + 128 * 136;  // [128][136]
    const int tid = threadIdx.x;
    const int nb = blockIdx.x * 128;

    {
        int nl = tid >> 2, part = tid & 3;
        int n = nb + nl; if (n >= N_NODESC) n = N_NODESC - 1;
        unsigned* Aw = (unsigned*)A + nl * 68 + part * 16;
        if (part < 2) {
            const float4* xs = (const float4*)(x + (size_t)n * XD + part * 32);
            #pragma unroll
            for (int q = 0; q < 8; ++q) {
                float4 v = xs[q];
                Aw[2 * q]     = pack2(v.x, v.y);
                Aw[2 * q + 1] = pack2(v.z, v.w);
            }
        } else {
            float inv = 1.0f / fmaxf(cnt[n], 1.0f);
            const float4* s = (const float4*)(sum2 + (size_t)n * OUTD + (part - 2) * 32);
            const float4* m = (const float4*)(mb2 + (part - 2) * 32);
            #pragma unroll
            for (int q = 0; q < 8; ++q) {
                float4 v = s[q]; float4 b = m[q];
                Aw[2 * q]     = pack2(fmaf(v.x, inv, b.x), fmaf(v.y, inv, b.y));
                Aw[2 * q + 1] = pack2(fmaf(v.z, inv, b.z), fmaf(v.w, inv, b.w));
            }
        }
    }
    __syncthreads();

    const int lane = tid & 63, l15 = lane & 15, l4 = lane >> 4;
    const int wave = tid >> 6;
    const int mh = (wave >> 2) * 64;
    const int nq = (wave & 3) * 32;

    f32x4 acc[4][2];
    #pragma unroll
    for (int m = 0; m < 4; ++m)
        #pragma unroll
        for (int n = 0; n < 2; ++n) acc[m][n] = (f32x4){0.f, 0.f, 0.f, 0.f};

    #pragma unroll
    for (int kc = 0; kc < 4; ++kc) {
        int kb = kc * 32 + l4 * 8;
        bf16x8 b0 = *(const bf16x8*)(bw1t + (nq + l15) * 128 + kb);
        bf16x8 b1v = *(const bf16x8*)(bw1t + (nq + 16 + l15) * 128 + kb);
        #pragma unroll
        for (int m = 0; m < 4; ++m) {
            bf16x8 a = *(const bf16x8*)(A + (mh + m * 16 + l15) * 136 + kb);
            acc[m][0] = __builtin_amdgcn_mfma_f32_16x16x32_bf16(a, b0, acc[m][0], 0, 0, 0);
            acc[m][1] = __builtin_amdgcn_mfma_f32_16x16x32_bf16(a, b1v, acc[m][1], 0, 0, 0);
        }
    }
    float bv0 = ab1[nq + l15], bv1 = ab1[nq + 16 + l15];
    #pragma unroll
    for (int m = 0; m < 4; ++m) {
        int rb = mh + m * 16 + l4 * 4;
        #pragma unroll
        for (int nn = 0; nn < 2; ++nn) {
            float bv = nn ? bv1 : bv0;
            int col = nq + nn * 16 + l15;
            #pragma unroll
            for (int r = 0; r < 4; ++r)
                H[(rb + r) * 136 + col] = f2bf(fmaxf(acc[m][nn][r] + bv, 0.f));
        }
    }
    __syncthreads();

    const int nw = (wave & 3) * 16;
    f32x4 acc2[4];
    #pragma unroll
    for (int m = 0; m < 4; ++m) acc2[m] = (f32x4){0.f, 0.f, 0.f, 0.f};
    #pragma unroll
    for (int kc = 0; kc < 4; ++kc) {
        int kb = kc * 32 + l4 * 8;
        bf16x8 b = *(const bf16x8*)(bw2t + (nw + l15) * 128 + kb);
        #pragma unroll
        for (int m = 0; m < 4; ++m) {
            bf16x8 a = *(const bf16x8*)(H + (mh + m * 16 + l15) * 136 + kb);
            acc2[m] = __builtin_amdgcn_mfma_f32_16x16x32_bf16(a, b, acc2[m], 0, 0, 0);
        }
    }
    float b2 = ab2[nw + l15];
    #pragma unroll
    for (int m = 0; m < 4; ++m) {
        int rb = mh + m * 16 + l4 * 4;
        #pragma unroll
        for (int r = 0; r < 4; ++r) {
            int node = nb + rb + r;
            if (node < N_NODESC)
                out[(size_t)node * OUTD + nw + l15] = acc2[m][r] + b2;
        }
    }
}

// ---------------------------------------------------------------------------
extern "C" void kernel_launch(void* const* d_in, const int* in_sizes, int n_in,
                              void* d_out, int out_size, void* d_ws, size_t ws_size,
                              hipStream_t stream)
{
    const float* x      = (const float*)d_in[0];
    const float* pos    = (const float*)d_in[1];
    const int*   ei     = (const int*)  d_in[2];
    const float* l1m_w1 = (const float*)d_in[3];
    const float* l1m_b1 = (const float*)d_in[4];
    const float* l1m_w2 = (const float*)d_in[5];
    const float* l1m_b2 = (const float*)d_in[6];
    const float* l1a_w1 = (const float*)d_in[7];
    const float* l1a_b1 = (const float*)d_in[8];
    const float* l1a_w2 = (const float*)d_in[9];
    const float* l1a_b2 = (const float*)d_in[10];
    const float* l2m_w1 = (const float*)d_in[11];
    const float* l2m_b1 = (const float*)d_in[12];
    const float* l2m_w2 = (const float*)d_in[13];
    const float* l2m_b2 = (const float*)d_in[14];
    const float* l2a_w1 = (const float*)d_in[15];
    const float* l2a_b1 = (const float*)d_in[16];
    const float* l2a_w2 = (const float*)d_in[17];
    const float* l2a_b2 = (const float*)d_in[18];

    float* ws    = (float*)d_ws;
    float* sum1  = ws;                                   // [N][64]
    float* sum2  = sum1 + (size_t)N_NODESC * CTXD;       // [N][64]
    float* ctxb  = sum2 + (size_t)N_NODESC * OUTD;       // [N][64] (unused hole)
    float* cnt_f = ctxb + (size_t)N_NODESC * CTXD;       // [NBINS]
    unsigned short* Pp   = (unsigned short*)(cnt_f + NBINS);    // [N][128]
    unsigned short* Qq   = Pp + (size_t)N_NODESC * 128;         // [N][128]
    unsigned short* Un   = Pp;   // L1 row-side (aliases Pp; dead before ctx_pq)
    unsigned short* U    = Qq;   // L1 col-side (aliases Qq)
    int2* eg2            = (int2*)Pp;  // bucket-scatter temp (dead before node_u)
    unsigned short* wp   = Qq + (size_t)N_NODESC * 128;         // 128*224
    unsigned short* wq   = wp + 128 * 224;
    unsigned short* w2t1 = wq + 128 * 224;               // 64*128
    unsigned short* w2t2 = w2t1 + 64 * 128;
    unsigned short* aw1t = w2t2 + 64 * 128;              // 128*64
    unsigned short* aw2t = aw1t + 128 * 64;              // 64*128
    unsigned short* bw1t = aw2t + 64 * 128;              // 128*128
    unsigned short* bw2t = bw1t + 128 * 128;             // 64*128
    int* gh     = (int*)(bw2t + 64 * 128);               // [NBKT]
    int* bbase  = gh + NBKT;                             // [NBKT]
    int* bcur   = bbase + NBKT;                          // [NBKT]
    int2* eg    = (int2*)(bcur + NBKT + 2);              // [E] (8B aligned)

    hipMemsetAsync(d_ws, 0, (size_t)2 * N_NODESC * 64 * sizeof(float), stream);
    hipMemsetAsync(gh, 0, NBKT * sizeof(int), stream);

    hipFuncSetAttribute((const void*)edge_mlp,
                        hipFuncAttributeMaxDynamicSharedMemorySize, EM_LDS);
    hipFuncSetAttribute((const void*)ctx_pq,
                        hipFuncAttributeMaxDynamicSharedMemorySize, CP_LDS);
    hipFuncSetAttribute((const void*)out_mfma,
                        hipFuncAttributeMaxDynamicSharedMemorySize, 2 * 128 * 136 * 2);

    bhist_k<<<256, 256, 0, stream>>>(ei, gh);
    bscan_k<<<1, 256, 0, stream>>>(gh, bbase, bcur);
    bscat_k<<<SC_BLOCKS, 1024, 0, stream>>>(ei, bcur, eg2);
    bsort_k<<<NBKT, 1024, 0, stream>>>(eg2, bbase, gh, eg, cnt_f);

    prep_weights<<<64, 256, 0, stream>>>(l2m_w1, l2m_w2, l1m_w2,
                                         l1a_w1, l1a_w2, l2a_w1, l2a_w2,
                                         wp, wq, w2t1, w2t2, aw1t, aw2t, bw1t, bw2t);

    node_u<<<(N_NODESC * 4 + 255) / 256, 256, 0, stream>>>(pos, l1m_w1, l1m_b1, U, Un);

    edge_mlp<<<EM_GRID, 512, EM_LDS, stream>>>(eg, Un, U, w2t1, sum1);

    ctx_pq<<<(N_NODESC + 127) / 128, 512, CP_LDS, stream>>>(
        sum1, cnt_f, l1m_b2, aw1t, l1a_b1, aw2t, l1a_b2,
        x, pos, wp, wq, l2m_b1, Pp, Qq);

    edge_mlp<<<EM_GRID, 512, EM_LDS, stream>>>(eg, Pp, Qq, w2t2, sum2);

    out_mfma<<<(N_NODESC + 127) / 128, 512, 2 * 128 * 136 * 2, stream>>>(
        x, sum2, cnt_f, l2m_b2, bw1t, l2a_b1, bw2t, l2a_b2, (float*)d_out);
}

// Round 12
// 218.649 us; speedup vs baseline: 1.3791x; 1.3791x over previous
//
#include <hip/hip_runtime.h>

#define N_NODESC 50000
#define N_EDGESC 800000
#define XD 64
#define HIDD 128
#define CTXD 64
#define OUTD 64
#define NBINS 50176   // 196 * 256
#define NBKT 196      // coarse buckets (row >> 8)
#define TILES 5       // 1250 blocks * 5 tiles * 128 edges

typedef __bf16 bf16x8 __attribute__((ext_vector_type(8)));
typedef float f32x4 __attribute__((ext_vector_type(4)));

__device__ __forceinline__ unsigned short f2bf(float x) {
    __bf16 b = (__bf16)x;
    return __builtin_bit_cast(unsigned short, b);
}
__device__ __forceinline__ unsigned int pack2(float lo, float hi) {
    return (unsigned int)f2bf(lo) | ((unsigned int)f2bf(hi) << 16);
}
__device__ __forceinline__ float bflo(unsigned v) {
    return __builtin_bit_cast(float, v << 16);
}
__device__ __forceinline__ float bfhi(unsigned v) {
    return __builtin_bit_cast(float, v & 0xFFFF0000u);
}

// lgkm-only barrier: leaves staged global loads (vmcnt) in flight
#define LBARRIER() asm volatile("s_waitcnt lgkmcnt(0)\ns_barrier" ::: "memory")

// ---------------------------------------------------------------------------
// Sort pass A: coarse 196-bucket histogram (LDS-aggregated, int4 reads)
// ---------------------------------------------------------------------------
__global__ __launch_bounds__(256) void bhist_k(const int* __restrict__ ei,
                                               int* __restrict__ gh)
{
    __shared__ int lh[NBKT];
    if (threadIdx.x < NBKT) lh[threadIdx.x] = 0;
    __syncthreads();
    int e = (blockIdx.x * 256 + threadIdx.x) * 4;
    int stride = gridDim.x * 256 * 4;
    for (; e < N_EDGESC; e += stride) {          // N_EDGESC % 4 == 0
        int4 r = *(const int4*)(ei + e);
        atomicAdd(&lh[r.x >> 8], 1);
        atomicAdd(&lh[r.y >> 8], 1);
        atomicAdd(&lh[r.z >> 8], 1);
        atomicAdd(&lh[r.w >> 8], 1);
    }
    __syncthreads();
    if (threadIdx.x < NBKT) atomicAdd(&gh[threadIdx.x], lh[threadIdx.x]);
}

// ---------------------------------------------------------------------------
// Sort pass B: scan 196 -> base + cursor
// ---------------------------------------------------------------------------
__global__ __launch_bounds__(256) void bscan_k(const int* __restrict__ gh,
                                               int* __restrict__ base,
                                               int* __restrict__ cursor)
{
    __shared__ int ps[256];
    int t = threadIdx.x;
    int v = (t < NBKT) ? gh[t] : 0;
    ps[t] = v;
    __syncthreads();
    for (int off = 1; off < 256; off <<= 1) {
        int u = (t >= off) ? ps[t - off] : 0;
        __syncthreads();
        ps[t] += u;
        __syncthreads();
    }
    if (t < NBKT) { base[t] = ps[t] - v; cursor[t] = ps[t] - v; }
}

// ---------------------------------------------------------------------------
// Sort pass C: block-aggregated reservation scatter (25k global atomics),
// int4 reads, 6272-edge (16B-aligned) chunks.
// ---------------------------------------------------------------------------
#define SC_BLOCKS 128
#define SC_CHUNK 6272   // multiple of 4; 128*6272 >= 800000

__global__ __launch_bounds__(1024) void bscat_k(const int* __restrict__ ei,
                                                int* __restrict__ cursor,
                                                int2* __restrict__ eg2)
{
    __shared__ int lh[NBKT], lbase[NBKT], lcur[NBKT];
    const int t = threadIdx.x;
    const int e0 = blockIdx.x * SC_CHUNK;
    const int e1 = min(e0 + SC_CHUNK, N_EDGESC);
    if (t < NBKT) lh[t] = 0;
    __syncthreads();
    for (int e = e0 + t * 4; e < e1; e += 4096) {
        if (e + 3 < e1) {
            int4 r = *(const int4*)(ei + e);
            atomicAdd(&lh[r.x >> 8], 1);
            atomicAdd(&lh[r.y >> 8], 1);
            atomicAdd(&lh[r.z >> 8], 1);
            atomicAdd(&lh[r.w >> 8], 1);
        } else {
            for (int i = e; i < e1; ++i) atomicAdd(&lh[ei[i] >> 8], 1);
        }
    }
    __syncthreads();
    if (t < NBKT) {
        lbase[t] = atomicAdd(&cursor[t], lh[t]);
        lcur[t] = 0;
    }
    __syncthreads();
    for (int e = e0 + t * 4; e < e1; e += 4096) {
        if (e + 3 < e1) {
            int4 r = *(const int4*)(ei + e);
            int4 c = *(const int4*)(ei + N_EDGESC + e);
            int b0 = r.x >> 8, b1 = r.y >> 8, b2 = r.z >> 8, b3 = r.w >> 8;
            int p0 = lbase[b0] + atomicAdd(&lcur[b0], 1);
            int p1 = lbase[b1] + atomicAdd(&lcur[b1], 1);
            int p2 = lbase[b2] + atomicAdd(&lcur[b2], 1);
            int p3 = lbase[b3] + atomicAdd(&lcur[b3], 1);
            eg2[p0] = make_int2(r.x, c.x);
            eg2[p1] = make_int2(r.y, c.y);
            eg2[p2] = make_int2(r.z, c.z);
            eg2[p3] = make_int2(r.w, c.w);
        } else {
            for (int i = e; i < e1; ++i) {
                int row = ei[i], col = ei[N_EDGESC + i];
                int b = row >> 8;
                int p = lbase[b] + atomicAdd(&lcur[b], 1);
                eg2[p] = make_int2(row, col);
            }
        }
    }
}

// ---------------------------------------------------------------------------
// Sort pass D: per-bucket (256-row) LDS counting sort -> row-sorted eg + cnt_f
// ---------------------------------------------------------------------------
__global__ __launch_bounds__(1024) void bsort_k(const int2* __restrict__ eg2,
                                                const int* __restrict__ base,
                                                const int* __restrict__ gh,
                                                int2* __restrict__ eg,
                                                float* __restrict__ cnt_f)
{
    __shared__ int h[256], pfx[256], cur[256];
    const int b = blockIdx.x;
    const int lo = base[b];
    const int n = gh[b];
    const int t = threadIdx.x;
    if (t < 256) h[t] = 0;
    __syncthreads();
    for (int i = t; i < n; i += 1024)
        atomicAdd(&h[eg2[lo + i].x & 255], 1);
    __syncthreads();
    if (t < 256) pfx[t] = h[t];
    __syncthreads();
    for (int off = 1; off < 256; off <<= 1) {
        int u = 0;
        if (t < 256 && t >= off) u = pfx[t - off];
        __syncthreads();
        if (t < 256) pfx[t] += u;
        __syncthreads();
    }
    if (t < 256) {
        cur[t] = pfx[t] - h[t];
        int row = b * 256 + t;
        if (row < N_NODESC) cnt_f[row] = (float)h[t];
    }
    __syncthreads();
    for (int i = t; i < n; i += 1024) {
        int2 rc = eg2[lo + i];
        int r = atomicAdd(&cur[rc.x & 255], 1);
        eg[lo + r] = rc;
    }
}

// ---------------------------------------------------------------------------
// Prep: bf16 weight transposes / combinations.
// ---------------------------------------------------------------------------
__global__ void prep_weights(const float* __restrict__ w1,
                             const float* __restrict__ l2m_w2,
                             const float* __restrict__ l1m_w2,
                             const float* __restrict__ l1a_w1,
                             const float* __restrict__ l1a_w2,
                             const float* __restrict__ l2a_w1,
                             const float* __restrict__ l2a_w2,
                             unsigned short* __restrict__ wp,
                             unsigned short* __restrict__ wq,
                             unsigned short* __restrict__ w2t1,
                             unsigned short* __restrict__ w2t2,
                             unsigned short* __restrict__ aw1t,
                             unsigned short* __restrict__ aw2t,
                             unsigned short* __restrict__ bw1t,
                             unsigned short* __restrict__ bw2t)
{
    int i0 = blockIdx.x * 256 + threadIdx.x;
    int stride = gridDim.x * 256;
    for (int idx = i0; idx < 128 * 224; idx += stride) {
        int n = idx / 224, k = idx - n * 224;
        float vp = 0.f, vq = 0.f;
        if (k < 64)        { vp = w1[k * 128 + n] - w1[(64 + k) * 128 + n];
                             vq = w1[(64 + k) * 128 + n]; }
        else if (k < 128)  { vp = w1[(130 + k - 64) * 128 + n]; }
        else if (k < 130)  { vp = -w1[(128 + (k - 128)) * 128 + n];
                             vq =  w1[(128 + (k - 128)) * 128 + n]; }
        wp[idx] = f2bf(vp);
        wq[idx] = f2bf(vq);
    }
    for (int idx = i0; idx < 64 * 128; idx += stride) {
        int n = idx >> 7, k = idx & 127;
        w2t1[idx] = f2bf(l1m_w2[k * 64 + n]);
        w2t2[idx] = f2bf(l2m_w2[k * 64 + n]);
        aw2t[idx] = f2bf(l1a_w2[k * 64 + n]);
        bw2t[idx] = f2bf(l2a_w2[k * 64 + n]);
    }
    for (int idx = i0; idx < 128 * 64; idx += stride) {
        int n = idx >> 6, k = idx & 63;
        aw1t[idx] = f2bf(l1a_w1[k * 128 + n]);
    }
    for (int idx = i0; idx < 128 * 128; idx += stride) {
        int n = idx >> 7, k = idx & 127;
        bw1t[idx] = f2bf(l2a_w1[k * 128 + n]);
    }
}

// ---------------------------------------------------------------------------
// node_u: U[n] = pos[n]@l1m_w1 (col side); Un[n] = b1 - U[n] (row side).
// ---------------------------------------------------------------------------
__global__ __launch_bounds__(256) void node_u(const float* __restrict__ pos,
                                              const float* __restrict__ w1,
                                              const float* __restrict__ b1,
                                              unsigned short* __restrict__ U,
                                              unsigned short* __restrict__ Un)
{
    int t = blockIdx.x * 256 + threadIdx.x;
    int n = t >> 2, part = t & 3;
    if (n >= N_NODESC) return;
    float2 p = *(const float2*)(pos + 2 * (size_t)n);
    const float4* wa = (const float4*)(w1 + part * 32);
    const float4* wb = (const float4*)(w1 + 128 + part * 32);
    const float4* bb = (const float4*)(b1 + part * 32);
    unsigned* Uw  = (unsigned*)U  + (size_t)n * 64 + part * 16;
    unsigned* Unw = (unsigned*)Un + (size_t)n * 64 + part * 16;
    #pragma unroll
    for (int q = 0; q < 8; ++q) {
        float4 a = wa[q], b = wb[q], f = bb[q];
        float h0 = fmaf(p.x, a.x, p.y * b.x);
        float h1 = fmaf(p.x, a.y, p.y * b.y);
        float h2 = fmaf(p.x, a.z, p.y * b.z);
        float h3 = fmaf(p.x, a.w, p.y * b.w);
        Uw[2 * q]      = pack2(h0, h1);
        Uw[2 * q + 1]  = pack2(h2, h3);
        Unw[2 * q]     = pack2(f.x - h0, f.y - h1);
        Unw[2 * q + 1] = pack2(f.z - h2, f.w - h3);
    }
}

// ---------------------------------------------------------------------------
// edge_mlp (r9 exact — measured 60.8 us): 1250 blocks, 5 tiles/block,
// launch-order scheduling (self-synchronizing tile window), dbuf H,
// lgkm-only barriers, register-staged gather pipeline, run-merged atomic
// segment-sum, bijective XCD swizzle.
// ---------------------------------------------------------------------------
#define EM_LDS (2 * 128 * 136 * 2 + 2 * 128 * 4)

__global__ __launch_bounds__(512, 4) void edge_mlp(
    const int2* __restrict__ eg,
    const unsigned short* __restrict__ Rr,   // row-side [N][128] (bias folded)
    const unsigned short* __restrict__ Cc,   // col-side [N][128]
    const unsigned short* __restrict__ w2t,  // [64][128]
    float* __restrict__ sumout)              // [N][64]
{
    extern __shared__ char smem[];
    unsigned short* H0 = (unsigned short*)smem;
    unsigned short* H1 = H0 + 128 * 136;
    int* rows0 = (int*)(smem + 2 * 128 * 136 * 2);
    int* rows1 = rows0 + 128;

    const int tid = threadIdx.x;
    const int el = tid >> 2, part = tid & 3;
    const int lane = tid & 63, l15 = lane & 15, l4 = lane >> 4;
    const int wave = tid >> 6;
    const int mh = (wave >> 2) * 64;
    const int nw = (wave & 3) * 16;

    // bijective XCD swizzle (m204): nwg may not divide by 8
    const int nwg = gridDim.x;
    const int q = nwg >> 3, rr8 = nwg & 7;
    const int xcd = blockIdx.x & 7, bi = blockIdx.x >> 3;
    const int swz = (xcd < rr8 ? xcd * (q + 1) : rr8 * (q + 1) + (xcd - rr8) * q) + bi;
    const size_t base = (size_t)swz * (TILES * 128);

    // B-operand fragments hoisted out of the tile loop
    bf16x8 bfrag[4];
    #pragma unroll
    for (int k = 0; k < 4; ++k)
        bfrag[k] = *(const bf16x8*)(w2t + (nw + l15) * 128 + k * 32 + l4 * 8);

    uint4 sR[2][4], sC[2][4];
    int2 e2[2];

    e2[0] = eg[base + el];
    e2[1] = eg[base + 128 + el];
    {
        const uint4* pr = (const uint4*)(Rr + (size_t)e2[0].x * 128 + part * 32);
        const uint4* pc = (const uint4*)(Cc + (size_t)e2[0].y * 128 + part * 32);
        #pragma unroll
        for (int qq = 0; qq < 4; ++qq) { sR[0][qq] = pr[qq]; sC[0][qq] = pc[qq]; }
    }

    #pragma unroll
    for (int t = 0; t < TILES; ++t) {
        const int b = t & 1;
        unsigned short* Hc = b ? H1 : H0;
        int* rowsc = b ? rows1 : rows0;
        const int rcur = e2[b].x;

        if (t + 1 < TILES) {   // issue next tile's gathers (stay in flight)
            const uint4* pr = (const uint4*)(Rr + (size_t)e2[b ^ 1].x * 128 + part * 32);
            const uint4* pc = (const uint4*)(Cc + (size_t)e2[b ^ 1].y * 128 + part * 32);
            #pragma unroll
            for (int qq = 0; qq < 4; ++qq) { sR[b ^ 1][qq] = pr[qq]; sC[b ^ 1][qq] = pc[qq]; }
        }
        if (t + 2 < TILES) e2[b] = eg[base + (size_t)(t + 2) * 128 + el];

        // pack h = relu(R + C) into H[b]
        if (part == 0) rowsc[el] = rcur;
        {
            uint4* Hw = (uint4*)((unsigned*)Hc + el * 68 + part * 16);
            #pragma unroll
            for (int qq = 0; qq < 4; ++qq) {
                uint4 pv = sR[b][qq], qv = sC[b][qq];
                unsigned w0 = pack2(fmaxf(bflo(pv.x) + bflo(qv.x), 0.f),
                                    fmaxf(bfhi(pv.x) + bfhi(qv.x), 0.f));
                unsigned w1v = pack2(fmaxf(bflo(pv.y) + bflo(qv.y), 0.f),
                                     fmaxf(bfhi(pv.y) + bfhi(qv.y), 0.f));
                unsigned w2v = pack2(fmaxf(bflo(pv.z) + bflo(qv.z), 0.f),
                                     fmaxf(bfhi(pv.z) + bfhi(qv.z), 0.f));
                unsigned w3v = pack2(fmaxf(bflo(pv.w) + bflo(qv.w), 0.f),
                                     fmaxf(bfhi(pv.w) + bfhi(qv.w), 0.f));
                Hw[qq] = make_uint4(w0, w1v, w2v, w3v);
            }
        }
        LBARRIER();

        f32x4 acc[4];
        #pragma unroll
        for (int m = 0; m < 4; ++m) acc[m] = (f32x4){0.f, 0.f, 0.f, 0.f};
        #pragma unroll
        for (int k = 0; k < 4; ++k) {
            int kb = k * 32 + l4 * 8;
            #pragma unroll
            for (int m = 0; m < 4; ++m) {
                bf16x8 a = *(const bf16x8*)(Hc + (mh + m * 16 + l15) * 136 + kb);
                acc[m] = __builtin_amdgcn_mfma_f32_16x16x32_bf16(a, bfrag[k], acc[m], 0, 0, 0);
            }
        }
        LBARRIER();   // all H[b] reads done before S overwrite

        float* S = (float*)Hc;   // [128][68]
        #pragma unroll
        for (int m = 0; m < 4; ++m) {
            int rb = mh + m * 16 + l4 * 4;
            #pragma unroll
            for (int r = 0; r < 4; ++r)
                S[(rb + r) * 68 + nw + l15] = acc[m][r];
        }
        LBARRIER();

        {   // run-merged segment reduction: thread = (col=lane, group=wave)
            const int c = lane;
            const int e0g = wave * 16;
            float sv[16];
            #pragma unroll
            for (int r = 0; r < 16; ++r) sv[r] = S[(e0g + r) * 68 + c];
            int rw[16];
            #pragma unroll
            for (int r = 0; r < 16; ++r)
                rw[r] = __builtin_amdgcn_readfirstlane(rowsc[e0g + r]);
            int cur = rw[0];
            float v = sv[0];
            #pragma unroll
            for (int r = 1; r < 16; ++r) {
                if (rw[r] == cur) { v += sv[r]; }
                else { unsafeAtomicAdd(sumout + (size_t)cur * 64 + c, v); cur = rw[r]; v = sv[r]; }
            }
            unsafeAtomicAdd(sumout + (size_t)cur * 64 + c, v);
        }
        // next iter packs the other H buffer; its last readers finished
        // before this tile's barriers -> no extra barrier needed.
    }
}

// ---------------------------------------------------------------------------
// ctx_pq (fused): phase 1 computes ctx = MLP(mean(m1)+l1m_b2) in-register;
// phase 2 builds the PQ A-tile [128][248]bf16 directly in LDS and computes
// P/Q with B read from L2-hot global. LDS 62 KB -> 2 blocks/CU.
// ---------------------------------------------------------------------------
#define CP_LDS (128 * 248 * 2)   // 63488 B; phase-1 A1(18432)+H1(34816) fit inside

__global__ __launch_bounds__(512, 4) void ctx_pq(
    const float* __restrict__ sum1, const float* __restrict__ cnt,
    const float* __restrict__ mb2,
    const unsigned short* __restrict__ aw1t, const float* __restrict__ ab1,
    const unsigned short* __restrict__ aw2t, const float* __restrict__ ab2,
    const float* __restrict__ x, const float* __restrict__ pos,
    const unsigned short* __restrict__ wp, const unsigned short* __restrict__ wq,
    const float* __restrict__ b1,
    unsigned short* __restrict__ Pp, unsigned short* __restrict__ Qq)
{
    extern __shared__ char smem[];
    unsigned short* A1 = (unsigned short*)smem;            // [128][72]
    unsigned short* H1 = (unsigned short*)(smem + 18432);  // [128][136]
    const int tid = threadIdx.x;
    const int nb = blockIdx.x * 128;
    const int nl = tid >> 2, part = tid & 3;
    const int lane = tid & 63, l15 = lane & 15, l4 = lane >> 4;
    const int wave = tid >> 6;
    const int mh = (wave >> 2) * 64;

    int n = nb + nl; if (n >= N_NODESC) n = N_NODESC - 1;

    float4 xr[4];
    {
        const float4* xs = (const float4*)(x + (size_t)n * XD + part * 16);
        #pragma unroll
        for (int q = 0; q < 4; ++q) xr[q] = xs[q];
    }
    float2 posr = *(const float2*)(pos + 2 * (size_t)n);

    // phase 1a: A1 = bf16(mean(sum1) + mb2)
    {
        float inv = 1.0f / fmaxf(cnt[n], 1.0f);
        const float4* s = (const float4*)(sum1 + (size_t)n * CTXD + part * 16);
        const float4* m = (const float4*)(mb2 + part * 16);
        unsigned* Aw = (unsigned*)A1 + nl * 36 + part * 8;
        #pragma unroll
        for (int q = 0; q < 4; ++q) {
            float4 v = s[q]; float4 b = m[q];
            Aw[2 * q]     = pack2(fmaf(v.x, inv, b.x), fmaf(v.y, inv, b.y));
            Aw[2 * q + 1] = pack2(fmaf(v.z, inv, b.z), fmaf(v.w, inv, b.w));
        }
    }
    __syncthreads();

    // phase 1b: hidden = relu(A1 @ aw1t + ab1) -> H1
    const int nq = (wave & 3) * 32;
    {
        f32x4 acc1[4][2];
        #pragma unroll
        for (int m = 0; m < 4; ++m)
            #pragma unroll
            for (int nn = 0; nn < 2; ++nn) acc1[m][nn] = (f32x4){0.f, 0.f, 0.f, 0.f};
        #pragma unroll
        for (int kc = 0; kc < 2; ++kc) {
            int kb = kc * 32 + l4 * 8;
            bf16x8 b0 = *(const bf16x8*)(aw1t + (nq + l15) * 64 + kb);
            bf16x8 b1v = *(const bf16x8*)(aw1t + (nq + 16 + l15) * 64 + kb);
            #pragma unroll
            for (int m = 0; m < 4; ++m) {
                bf16x8 a = *(const bf16x8*)(A1 + (mh + m * 16 + l15) * 72 + kb);
                acc1[m][0] = __builtin_amdgcn_mfma_f32_16x16x32_bf16(a, b0, acc1[m][0], 0, 0, 0);
                acc1[m][1] = __builtin_amdgcn_mfma_f32_16x16x32_bf16(a, b1v, acc1[m][1], 0, 0, 0);
            }
        }
        float bv0 = ab1[nq + l15], bv1 = ab1[nq + 16 + l15];
        #pragma unroll
        for (int m = 0; m < 4; ++m) {
            int rb = mh + m * 16 + l4 * 4;
            #pragma unroll
            for (int nn = 0; nn < 2; ++nn) {
                float bv = nn ? bv1 : bv0;
                int col = nq + nn * 16 + l15;
                #pragma unroll
                for (int r = 0; r < 4; ++r)
                    H1[(rb + r) * 136 + col] = f2bf(fmaxf(acc1[m][nn][r] + bv, 0.f));
            }
        }
    }
    __syncthreads();

    // phase 1c: ctx = H1 @ aw2t + ab2 (kept in acc2 registers)
    const int nw = (wave & 3) * 16;
    f32x4 acc2[4];
    #pragma unroll
    for (int m = 0; m < 4; ++m) acc2[m] = (f32x4){0.f, 0.f, 0.f, 0.f};
    #pragma unroll
    for (int kc = 0; kc < 4; ++kc) {
        int kb = kc * 32 + l4 * 8;
        bf16x8 b = *(const bf16x8*)(aw2t + (nw + l15) * 128 + kb);
        #pragma unroll
        for (int m = 0; m < 4; ++m) {
            bf16x8 a = *(const bf16x8*)(H1 + (mh + m * 16 + l15) * 136 + kb);
            acc2[m] = __builtin_amdgcn_mfma_f32_16x16x32_bf16(a, b, acc2[m], 0, 0, 0);
        }
    }
    float cb2 = ab2[nw + l15];
    __syncthreads();   // all A1/H1 reads complete before A2 overwrites

    // phase 2a: build A2 [128 nodes][248 shorts]: x | ctx | pos | zeros
    {
        unsigned* Aw = (unsigned*)smem + nl * 124;
        #pragma unroll
        for (int q = 0; q < 4; ++q) {
            Aw[part * 8 + 2 * q]     = pack2(xr[q].x, xr[q].y);
            Aw[part * 8 + 2 * q + 1] = pack2(xr[q].z, xr[q].w);
        }
        if (part < 3) {
            #pragma unroll
            for (int z = 0; z < 15; ++z) Aw[65 + part * 15 + z] = 0u;
        } else {
            #pragma unroll
            for (int z = 0; z < 14; ++z) Aw[110 + z] = 0u;
            Aw[64] = pack2(posr.x, posr.y);   // feats 128,129
        }
    }
    {   // ctx (bf16) into feats 64..127 straight from accumulators
        unsigned short* A2s = (unsigned short*)smem;
        #pragma unroll
        for (int m = 0; m < 4; ++m) {
            int rb = mh + m * 16 + l4 * 4;
            #pragma unroll
            for (int r = 0; r < 4; ++r)
                A2s[(rb + r) * 248 + 64 + nw + l15] = f2bf(acc2[m][r] + cb2);
        }
    }
    __syncthreads();

    // phase 2b: P/Q MFMAs; B operands from L2-hot global
    const int nq2 = wave & 3;
    f32x4 acc[4][4];
    #pragma unroll
    for (int m = 0; m < 4; ++m)
        #pragma unroll
        for (int nn = 0; nn < 4; ++nn) acc[m][nn] = (f32x4){0.f, 0.f, 0.f, 0.f};

    if (nq2 < 2) {
        const int cb = nq2 * 64;
        #pragma unroll
        for (int kc = 0; kc < 7; ++kc) {
            int ks = kc * 32 + l4 * 8;        // short offset within 224-row
            int ko = ks * 2;                  // byte offset within 496-stride
            bf16x8 b0 = *(const bf16x8*)(wp + (cb + l15) * 224 + ks);
            bf16x8 b1v = *(const bf16x8*)(wp + (cb + 16 + l15) * 224 + ks);
            bf16x8 b2v = *(const bf16x8*)(wp + (cb + 32 + l15) * 224 + ks);
            bf16x8 b3v = *(const bf16x8*)(wp + (cb + 48 + l15) * 224 + ks);
            #pragma unroll
            for (int m = 0; m < 4; ++m) {
                bf16x8 a = *(const bf16x8*)(smem + (mh + m * 16 + l15) * 496 + ko);
                acc[m][0] = __builtin_amdgcn_mfma_f32_16x16x32_bf16(a, b0, acc[m][0], 0, 0, 0);
                acc[m][1] = __builtin_amdgcn_mfma_f32_16x16x32_bf16(a, b1v, acc[m][1], 0, 0, 0);
                acc[m][2] = __builtin_amdgcn_mfma_f32_16x16x32_bf16(a, b2v, acc[m][2], 0, 0, 0);
                acc[m][3] = __builtin_amdgcn_mfma_f32_16x16x32_bf16(a, b3v, acc[m][3], 0, 0, 0);
            }
        }
        #pragma unroll
        for (int nn = 0; nn < 4; ++nn) {
            int col = cb + nn * 16 + l15;
            float bb = b1[col];
            #pragma unroll
            for (int m = 0; m < 4; ++m) {
                int rb = mh + m * 16 + l4 * 4;
                #pragma unroll
                for (int r = 0; r < 4; ++r) {
                    int node = nb + rb + r;
                    if (node < N_NODESC)
                        Pp[(size_t)node * 128 + col] = f2bf(acc[m][nn][r] + bb);
                }
            }
        }
    } else {
        const int cb = (nq2 - 2) * 64;
        const int kcs[3] = {0, 1, 4};
        #pragma unroll
        for (int tk2 = 0; tk2 < 3; ++tk2) {
            int kc = kcs[tk2];
            int ks = kc * 32 + l4 * 8;
            bf16x8 b0 = *(const bf16x8*)(wq + (cb + l15) * 224 + ks);
            bf16x8 b1v = *(const bf16x8*)(wq + (cb + 16 + l15) * 224 + ks);
            bf16x8 b2v = *(const bf16x8*)(wq + (cb + 32 + l15) * 224 + ks);
            bf16x8 b3v = *(const bf16x8*)(wq + (cb + 48 + l15) * 224 + ks);
            #pragma unroll
            for (int m = 0; m < 4; ++m) {
                bf16x8 a = *(const bf16x8*)(smem + (mh + m * 16 + l15) * 496 + ks * 2);
                acc[m][0] = __builtin_amdgcn_mfma_f32_16x16x32_bf16(a, b0, acc[m][0], 0, 0, 0);
                acc[m][1] = __builtin_amdgcn_mfma_f32_16x16x32_bf16(a, b1v, acc[m][1], 0, 0, 0);
                acc[m][2] = __builtin_amdgcn_mfma_f32_16x16x32_bf16(a, b2v, acc[m][2], 0, 0, 0);
                acc[m][3] = __builtin_amdgcn_mfma_f32_16x16x32_bf16(a, b3v, acc[m][3], 0, 0, 0);
            }
        }
        #pragma unroll
        for (int nn = 0; nn < 4; ++nn) {
            int col = cb + nn * 16 + l15;
            #pragma unroll
            for (int m = 0; m < 4; ++m) {
                int rb = mh + m * 16 + l4 * 4;
                #pragma unroll
                for (int r = 0; r < 4; ++r) {
                    int node = nb + rb + r;
                    if (node < N_NODESC)
                        Qq[(size_t)node * 128 + col] = f2bf(acc[m][nn][r]);
                }
            }
        }
    }
}

// ---------------------------------------------------------------------------
// out = MLP([x, mean(m2)+l2m_b2]) (128 -> 128 -> 64), MFMA
// ---------------------------------------------------------------------------
__global__ __launch_bounds__(512) void out_mfma(
    const float* __restrict__ x, const float* __restrict__ sum2,
    const float* __restrict__ cnt, const float* __restrict__ mb2,
    const unsigned short* __restrict__ bw1t, const float* __restrict__ ab1,
    const unsigned short* __restrict__ bw2t, const float* __restrict__ ab2,
    float* __restrict__ out)
{
    extern __shared__ unsigned short sm[];
    unsigned short* A = sm;              // [128][136]
    unsigned short* H = sm + 128 * 136;  // [128][136]
    const int tid = threadIdx.x;
    const int nb = blockIdx.x * 128;

    {
        int nl = tid >> 2, part = tid & 3;
        int n = nb + nl; if (n >= N_NODESC) n = N_NODESC - 1;
        unsigned* Aw = (unsigned*)A + nl * 68 + part * 16;
        if (part < 2) {
            const float4* xs = (const float4*)(x + (size_t)n * XD + part * 32);
            #pragma unroll
            for (int q = 0; q < 8; ++q) {
                float4 v = xs[q];
                Aw[2 * q]     = pack2(v.x, v.y);
                Aw[2 * q + 1] = pack2(v.z, v.w);
            }
        } else {
            float inv = 1.0f / fmaxf(cnt[n], 1.0f);
            const float4* s = (const float4*)(sum2 + (size_t)n * OUTD + (part - 2) * 32);
            const float4* m = (const float4*)(mb2 + (part - 2) * 32);
            #pragma unroll
            for (int q = 0; q < 8; ++q) {
                float4 v = s[q]; float4 b = m[q];
                Aw[2 * q]     = pack2(fmaf(v.x, inv, b.x), fmaf(v.y, inv, b.y));
                Aw[2 * q + 1] = pack2(fmaf(v.z, inv, b.z), fmaf(v.w, inv, b.w));
            }
        }
    }
    __syncthreads();

    const int lane = tid & 63, l15 = lane & 15, l4 = lane >> 4;
    const int wave = tid >> 6;
    const int mh = (wave >> 2) * 64;
    const int nq = (wave & 3) * 32;

    f32x4 acc[4][2];
    #pragma unroll
    for (int m = 0; m < 4; ++m)
        #pragma unroll
        for (int n = 0; n < 2; ++n) acc[m][n] = (f32x4){0.f, 0.f, 0.f, 0.f};

    #pragma unroll
    for (int kc = 0; kc < 4; ++kc) {
        int kb = kc * 32 + l4 * 8;
        bf16x8 b0 = *(const bf16x8*)(bw1t + (nq + l15) * 128 + kb);
        bf16x8 b1v = *(const bf16x8*)(bw1t + (nq + 16 + l15) * 128 + kb);
        #pragma unroll
        for (int m = 0; m < 4; ++m) {
            bf16x8 a = *(const bf16x8*)(A + (mh + m * 16 + l15) * 136 + kb);
            acc[m][0] = __builtin_amdgcn_mfma_f32_16x16x32_bf16(a, b0, acc[m][0], 0, 0, 0);
            acc[m][1] = __builtin_amdgcn_mfma_f32_16x16x32_bf16(a, b1v, acc[m][1], 0, 0, 0);
        }
    }
    float bv0 = ab1[nq + l15], bv1 = ab1[nq + 16 + l15];
    #pragma unroll
    for (int m = 0; m < 4; ++m) {
        int rb = mh + m * 16 + l4 * 4;
        #pragma unroll
        for (int nn = 0; nn < 2; ++nn) {
            float bv = nn ? bv1 : bv0;
            int col = nq + nn * 16 + l15;
            #pragma unroll
            for (int r = 0; r < 4; ++r)
                H[(rb + r) * 136 + col] = f2bf(fmaxf(acc[m][nn][r] + bv, 0.f));
        }
    }
    __syncthreads();

    const int nw = (wave & 3) * 16;
    f32x4 acc2[4];
    #pragma unroll
    for (int m = 0; m < 4; ++m) acc2[m] = (f32x4){0.f, 0.f, 0.f, 0.f};
    #pragma unroll
    for (int kc = 0; kc < 4; ++kc) {
        int kb = kc * 32 + l4 * 8;
        bf16x8 b = *(const bf16x8*)(bw2t + (nw + l15) * 128 + kb);
        #pragma unroll
        for (int m = 0; m < 4; ++m) {
            bf16x8 a = *(const bf16x8*)(H + (mh + m * 16 + l15) * 136 + kb);
            acc2[m] = __builtin_amdgcn_mfma_f32_16x16x32_bf16(a, b, acc2[m], 0, 0, 0);
        }
    }
    float b2 = ab2[nw + l15];
    #pragma unroll
    for (int m = 0; m < 4; ++m) {
        int rb = mh + m * 16 + l4 * 4;
        #pragma unroll
        for (int r = 0; r < 4; ++r) {
            int node = nb + rb + r;
            if (node < N_NODESC)
                out[(size_t)node * OUTD + nw + l15] = acc2[m][r] + b2;
        }
    }
}

// ---------------------------------------------------------------------------
extern "C" void kernel_launch(void* const* d_in, const int* in_sizes, int n_in,
                              void* d_out, int out_size, void* d_ws, size_t ws_size,
                              hipStream_t stream)
{
    const float* x      = (const float*)d_in[0];
    const float* pos    = (const float*)d_in[1];
    const int*   ei     = (const int*)  d_in[2];
    const float* l1m_w1 = (const float*)d_in[3];
    const float* l1m_b1 = (const float*)d_in[4];
    const float* l1m_w2 = (const float*)d_in[5];
    const float* l1m_b2 = (const float*)d_in[6];
    const float* l1a_w1 = (const float*)d_in[7];
    const float* l1a_b1 = (const float*)d_in[8];
    const float* l1a_w2 = (const float*)d_in[9];
    const float* l1a_b2 = (const float*)d_in[10];
    const float* l2m_w1 = (const float*)d_in[11];
    const float* l2m_b1 = (const float*)d_in[12];
    const float* l2m_w2 = (const float*)d_in[13];
    const float* l2m_b2 = (const float*)d_in[14];
    const float* l2a_w1 = (const float*)d_in[15];
    const float* l2a_b1 = (const float*)d_in[16];
    const float* l2a_w2 = (const float*)d_in[17];
    const float* l2a_b2 = (const float*)d_in[18];

    float* ws    = (float*)d_ws;
    float* sum1  = ws;                                   // [N][64]
    float* sum2  = sum1 + (size_t)N_NODESC * CTXD;       // [N][64]
    float* ctxb  = sum2 + (size_t)N_NODESC * OUTD;       // [N][64] (unused hole)
    float* cnt_f = ctxb + (size_t)N_NODESC * CTXD;       // [NBINS]
    unsigned short* Pp   = (unsigned short*)(cnt_f + NBINS);    // [N][128]
    unsigned short* Qq   = Pp + (size_t)N_NODESC * 128;         // [N][128]
    unsigned short* Un   = Pp;   // L1 row-side (aliases Pp; dead before ctx_pq)
    unsigned short* U    = Qq;   // L1 col-side (aliases Qq)
    int2* eg2            = (int2*)Pp;  // bucket-scatter temp (dead before node_u)
    unsigned short* wp   = Qq + (size_t)N_NODESC * 128;         // 128*224
    unsigned short* wq   = wp + 128 * 224;
    unsigned short* w2t1 = wq + 128 * 224;               // 64*128
    unsigned short* w2t2 = w2t1 + 64 * 128;
    unsigned short* aw1t = w2t2 + 64 * 128;              // 128*64
    unsigned short* aw2t = aw1t + 128 * 64;              // 64*128
    unsigned short* bw1t = aw2t + 64 * 128;              // 128*128
    unsigned short* bw2t = bw1t + 128 * 128;             // 64*128
    int* gh     = (int*)(bw2t + 64 * 128);               // [NBKT]
    int* bbase  = gh + NBKT;                             // [NBKT]
    int* bcur   = bbase + NBKT;                          // [NBKT]
    int2* eg    = (int2*)(bcur + NBKT + 2);              // [E] (8B aligned)

    hipMemsetAsync(d_ws, 0, (size_t)2 * N_NODESC * 64 * sizeof(float), stream);
    hipMemsetAsync(gh, 0, NBKT * sizeof(int), stream);

    hipFuncSetAttribute((const void*)edge_mlp,
                        hipFuncAttributeMaxDynamicSharedMemorySize, EM_LDS);
    hipFuncSetAttribute((const void*)ctx_pq,
                        hipFuncAttributeMaxDynamicSharedMemorySize, CP_LDS);
    hipFuncSetAttribute((const void*)out_mfma,
                        hipFuncAttributeMaxDynamicSharedMemorySize, 2 * 128 * 136 * 2);

    bhist_k<<<256, 256, 0, stream>>>(ei, gh);
    bscan_k<<<1, 256, 0, stream>>>(gh, bbase, bcur);
    bscat_k<<<SC_BLOCKS, 1024, 0, stream>>>(ei, bcur, eg2);
    bsort_k<<<NBKT, 1024, 0, stream>>>(eg2, bbase, gh, eg, cnt_f);

    prep_weights<<<64, 256, 0, stream>>>(l2m_w1, l2m_w2, l1m_w2,
                                         l1a_w1, l1a_w2, l2a_w1, l2a_w2,
                                         wp, wq, w2t1, w2t2, aw1t, aw2t, bw1t, bw2t);

    node_u<<<(N_NODESC * 4 + 255) / 256, 256, 0, stream>>>(pos, l1m_w1, l1m_b1, U, Un);

    edge_mlp<<<N_EDGESC / (128 * TILES), 512, EM_LDS, stream>>>(
        eg, Un, U, w2t1, sum1);

    ctx_pq<<<(N_NODESC + 127) / 128, 512, CP_LDS, stream>>>(
        sum1, cnt_f, l1m_b2, aw1t, l1a_b1, aw2t, l1a_b2,
        x, pos, wp, wq, l2m_b1, Pp, Qq);

    edge_mlp<<<N_EDGESC / (128 * TILES), 512, EM_LDS, stream>>>(
        eg, Pp, Qq, w2t2, sum2);

    out_mfma<<<(N_NODESC + 127) / 128, 512, 2 * 128 * 136 * 2, stream>>>(
        x, sum2, cnt_f, l2m_b2, bw1t, l2a_b1, bw2t, l2a_b2, (float*)d_out);
}

// Round 13
// 214.300 us; speedup vs baseline: 1.4071x; 1.0203x over previous
//
#include <hip/hip_runtime.h>

#define N_NODESC 50000
#define N_EDGESC 800000
#define XD 64
#define HIDD 128
#define CTXD 64
#define OUTD 64
#define NBINS 50176   // 196 * 256
#define NBKT 196      // coarse buckets (row >> 8)
#define TILES 5       // 1250 blocks * 5 tiles * 128 edges

typedef __bf16 bf16x8 __attribute__((ext_vector_type(8)));
typedef float f32x4 __attribute__((ext_vector_type(4)));

__device__ __forceinline__ unsigned short f2bf(float x) {
    __bf16 b = (__bf16)x;
    return __builtin_bit_cast(unsigned short, b);
}
__device__ __forceinline__ unsigned int pack2(float lo, float hi) {
    return (unsigned int)f2bf(lo) | ((unsigned int)f2bf(hi) << 16);
}
__device__ __forceinline__ float bflo(unsigned v) {
    return __builtin_bit_cast(float, v << 16);
}
__device__ __forceinline__ float bfhi(unsigned v) {
    return __builtin_bit_cast(float, v & 0xFFFF0000u);
}

// lgkm-only barrier: leaves staged global loads (vmcnt) in flight
#define LBARRIER() asm volatile("s_waitcnt lgkmcnt(0)\ns_barrier" ::: "memory")

// ---------------------------------------------------------------------------
// Sort pass A: coarse 196-bucket histogram (LDS-aggregated, int4 reads)
// ---------------------------------------------------------------------------
__global__ __launch_bounds__(256) void bhist_k(const int* __restrict__ ei,
                                               int* __restrict__ gh)
{
    __shared__ int lh[NBKT];
    if (threadIdx.x < NBKT) lh[threadIdx.x] = 0;
    __syncthreads();
    int e = (blockIdx.x * 256 + threadIdx.x) * 4;
    int stride = gridDim.x * 256 * 4;
    for (; e < N_EDGESC; e += stride) {          // N_EDGESC % 4 == 0
        int4 r = *(const int4*)(ei + e);
        atomicAdd(&lh[r.x >> 8], 1);
        atomicAdd(&lh[r.y >> 8], 1);
        atomicAdd(&lh[r.z >> 8], 1);
        atomicAdd(&lh[r.w >> 8], 1);
    }
    __syncthreads();
    if (threadIdx.x < NBKT) atomicAdd(&gh[threadIdx.x], lh[threadIdx.x]);
}

// ---------------------------------------------------------------------------
// Sort pass B: scan 196 -> base + cursor
// ---------------------------------------------------------------------------
__global__ __launch_bounds__(256) void bscan_k(const int* __restrict__ gh,
                                               int* __restrict__ base,
                                               int* __restrict__ cursor)
{
    __shared__ int ps[256];
    int t = threadIdx.x;
    int v = (t < NBKT) ? gh[t] : 0;
    ps[t] = v;
    __syncthreads();
    for (int off = 1; off < 256; off <<= 1) {
        int u = (t >= off) ? ps[t - off] : 0;
        __syncthreads();
        ps[t] += u;
        __syncthreads();
    }
    if (t < NBKT) { base[t] = ps[t] - v; cursor[t] = ps[t] - v; }
}

// ---------------------------------------------------------------------------
// Sort pass C: block-aggregated reservation scatter (25k global atomics),
// int4 reads, 6272-edge (16B-aligned) chunks.
// ---------------------------------------------------------------------------
#define SC_BLOCKS 128
#define SC_CHUNK 6272   // multiple of 4; 128*6272 >= 800000

__global__ __launch_bounds__(1024) void bscat_k(const int* __restrict__ ei,
                                                int* __restrict__ cursor,
                                                int2* __restrict__ eg2)
{
    __shared__ int lh[NBKT], lbase[NBKT], lcur[NBKT];
    const int t = threadIdx.x;
    const int e0 = blockIdx.x * SC_CHUNK;
    const int e1 = min(e0 + SC_CHUNK, N_EDGESC);
    if (t < NBKT) lh[t] = 0;
    __syncthreads();
    for (int e = e0 + t * 4; e < e1; e += 4096) {
        if (e + 3 < e1) {
            int4 r = *(const int4*)(ei + e);
            atomicAdd(&lh[r.x >> 8], 1);
            atomicAdd(&lh[r.y >> 8], 1);
            atomicAdd(&lh[r.z >> 8], 1);
            atomicAdd(&lh[r.w >> 8], 1);
        } else {
            for (int i = e; i < e1; ++i) atomicAdd(&lh[ei[i] >> 8], 1);
        }
    }
    __syncthreads();
    if (t < NBKT) {
        lbase[t] = atomicAdd(&cursor[t], lh[t]);
        lcur[t] = 0;
    }
    __syncthreads();
    for (int e = e0 + t * 4; e < e1; e += 4096) {
        if (e + 3 < e1) {
            int4 r = *(const int4*)(ei + e);
            int4 c = *(const int4*)(ei + N_EDGESC + e);
            int b0 = r.x >> 8, b1 = r.y >> 8, b2 = r.z >> 8, b3 = r.w >> 8;
            int p0 = lbase[b0] + atomicAdd(&lcur[b0], 1);
            int p1 = lbase[b1] + atomicAdd(&lcur[b1], 1);
            int p2 = lbase[b2] + atomicAdd(&lcur[b2], 1);
            int p3 = lbase[b3] + atomicAdd(&lcur[b3], 1);
            eg2[p0] = make_int2(r.x, c.x);
            eg2[p1] = make_int2(r.y, c.y);
            eg2[p2] = make_int2(r.z, c.z);
            eg2[p3] = make_int2(r.w, c.w);
        } else {
            for (int i = e; i < e1; ++i) {
                int row = ei[i], col = ei[N_EDGESC + i];
                int b = row >> 8;
                int p = lbase[b] + atomicAdd(&lcur[b], 1);
                eg2[p] = make_int2(row, col);
            }
        }
    }
}

// ---------------------------------------------------------------------------
// Sort pass D: per-bucket (256-row) LDS counting sort -> row-sorted eg + cnt_f
// ---------------------------------------------------------------------------
__global__ __launch_bounds__(1024) void bsort_k(const int2* __restrict__ eg2,
                                                const int* __restrict__ base,
                                                const int* __restrict__ gh,
                                                int2* __restrict__ eg,
                                                float* __restrict__ cnt_f)
{
    __shared__ int h[256], pfx[256], cur[256];
    const int b = blockIdx.x;
    const int lo = base[b];
    const int n = gh[b];
    const int t = threadIdx.x;
    if (t < 256) h[t] = 0;
    __syncthreads();
    for (int i = t; i < n; i += 1024)
        atomicAdd(&h[eg2[lo + i].x & 255], 1);
    __syncthreads();
    if (t < 256) pfx[t] = h[t];
    __syncthreads();
    for (int off = 1; off < 256; off <<= 1) {
        int u = 0;
        if (t < 256 && t >= off) u = pfx[t - off];
        __syncthreads();
        if (t < 256) pfx[t] += u;
        __syncthreads();
    }
    if (t < 256) {
        cur[t] = pfx[t] - h[t];
        int row = b * 256 + t;
        if (row < N_NODESC) cnt_f[row] = (float)h[t];
    }
    __syncthreads();
    for (int i = t; i < n; i += 1024) {
        int2 rc = eg2[lo + i];
        int r = atomicAdd(&cur[rc.x & 255], 1);
        eg[lo + r] = rc;
    }
}

// ---------------------------------------------------------------------------
// prep_node_u (merged): blocks 0..63 do bf16 weight transposes/combinations;
// blocks 64.. do node_u (U = pos@l1m_w1 ; Un = b1 - U). Independent work.
// ---------------------------------------------------------------------------
#define PU_PREP_BLOCKS 64
#define PU_NODE_BLOCKS ((N_NODESC * 4 + 255) / 256)

__global__ __launch_bounds__(256) void prep_node_u(
    const float* __restrict__ w1,       // l2m_w1
    const float* __restrict__ l2m_w2,
    const float* __restrict__ l1m_w2,
    const float* __restrict__ l1a_w1,
    const float* __restrict__ l1a_w2,
    const float* __restrict__ l2a_w1,
    const float* __restrict__ l2a_w2,
    const float* __restrict__ pos,
    const float* __restrict__ u_w1,     // l1m_w1
    const float* __restrict__ u_b1,     // l1m_b1
    unsigned short* __restrict__ wp,
    unsigned short* __restrict__ wq,
    unsigned short* __restrict__ w2t1,
    unsigned short* __restrict__ w2t2,
    unsigned short* __restrict__ aw1t,
    unsigned short* __restrict__ aw2t,
    unsigned short* __restrict__ bw1t,
    unsigned short* __restrict__ bw2t,
    unsigned short* __restrict__ U,
    unsigned short* __restrict__ Un)
{
    if (blockIdx.x < PU_PREP_BLOCKS) {
        int i0 = blockIdx.x * 256 + threadIdx.x;
        int stride = PU_PREP_BLOCKS * 256;
        for (int idx = i0; idx < 128 * 224; idx += stride) {
            int n = idx / 224, k = idx - n * 224;
            float vp = 0.f, vq = 0.f;
            if (k < 64)        { vp = w1[k * 128 + n] - w1[(64 + k) * 128 + n];
                                 vq = w1[(64 + k) * 128 + n]; }
            else if (k < 128)  { vp = w1[(130 + k - 64) * 128 + n]; }
            else if (k < 130)  { vp = -w1[(128 + (k - 128)) * 128 + n];
                                 vq =  w1[(128 + (k - 128)) * 128 + n]; }
            wp[idx] = f2bf(vp);
            wq[idx] = f2bf(vq);
        }
        for (int idx = i0; idx < 64 * 128; idx += stride) {
            int n = idx >> 7, k = idx & 127;
            w2t1[idx] = f2bf(l1m_w2[k * 64 + n]);
            w2t2[idx] = f2bf(l2m_w2[k * 64 + n]);
            aw2t[idx] = f2bf(l1a_w2[k * 64 + n]);
            bw2t[idx] = f2bf(l2a_w2[k * 64 + n]);
        }
        for (int idx = i0; idx < 128 * 64; idx += stride) {
            int n = idx >> 6, k = idx & 63;
            aw1t[idx] = f2bf(l1a_w1[k * 128 + n]);
        }
        for (int idx = i0; idx < 128 * 128; idx += stride) {
            int n = idx >> 7, k = idx & 127;
            bw1t[idx] = f2bf(l2a_w1[k * 128 + n]);
        }
    } else {
        int t = (blockIdx.x - PU_PREP_BLOCKS) * 256 + threadIdx.x;
        int n = t >> 2, part = t & 3;
        if (n >= N_NODESC) return;
        float2 p = *(const float2*)(pos + 2 * (size_t)n);
        const float4* wa = (const float4*)(u_w1 + part * 32);
        const float4* wb = (const float4*)(u_w1 + 128 + part * 32);
        const float4* bb = (const float4*)(u_b1 + part * 32);
        unsigned* Uw  = (unsigned*)U  + (size_t)n * 64 + part * 16;
        unsigned* Unw = (unsigned*)Un + (size_t)n * 64 + part * 16;
        #pragma unroll
        for (int q = 0; q < 8; ++q) {
            float4 a = wa[q], b = wb[q], f = bb[q];
            float h0 = fmaf(p.x, a.x, p.y * b.x);
            float h1 = fmaf(p.x, a.y, p.y * b.y);
            float h2 = fmaf(p.x, a.z, p.y * b.z);
            float h3 = fmaf(p.x, a.w, p.y * b.w);
            Uw[2 * q]      = pack2(h0, h1);
            Uw[2 * q + 1]  = pack2(h2, h3);
            Unw[2 * q]     = pack2(f.x - h0, f.y - h1);
            Unw[2 * q + 1] = pack2(f.z - h2, f.w - h3);
        }
    }
}

// ---------------------------------------------------------------------------
// edge_mlp (r9 exact — measured 60.8 us): 1250 blocks, 5 tiles/block,
// launch-order scheduling (self-synchronizing tile window), dbuf H,
// lgkm-only barriers, register-staged gather pipeline, run-merged atomic
// segment-sum, bijective XCD swizzle.
// ---------------------------------------------------------------------------
#define EM_LDS (2 * 128 * 136 * 2 + 2 * 128 * 4)

__global__ __launch_bounds__(512, 4) void edge_mlp(
    const int2* __restrict__ eg,
    const unsigned short* __restrict__ Rr,   // row-side [N][128] (bias folded)
    const unsigned short* __restrict__ Cc,   // col-side [N][128]
    const unsigned short* __restrict__ w2t,  // [64][128]
    float* __restrict__ sumout)              // [N][64]
{
    extern __shared__ char smem[];
    unsigned short* H0 = (unsigned short*)smem;
    unsigned short* H1 = H0 + 128 * 136;
    int* rows0 = (int*)(smem + 2 * 128 * 136 * 2);
    int* rows1 = rows0 + 128;

    const int tid = threadIdx.x;
    const int el = tid >> 2, part = tid & 3;
    const int lane = tid & 63, l15 = lane & 15, l4 = lane >> 4;
    const int wave = tid >> 6;
    const int mh = (wave >> 2) * 64;
    const int nw = (wave & 3) * 16;

    // bijective XCD swizzle (m204): nwg may not divide by 8
    const int nwg = gridDim.x;
    const int q = nwg >> 3, rr8 = nwg & 7;
    const int xcd = blockIdx.x & 7, bi = blockIdx.x >> 3;
    const int swz = (xcd < rr8 ? xcd * (q + 1) : rr8 * (q + 1) + (xcd - rr8) * q) + bi;
    const size_t base = (size_t)swz * (TILES * 128);

    // B-operand fragments hoisted out of the tile loop
    bf16x8 bfrag[4];
    #pragma unroll
    for (int k = 0; k < 4; ++k)
        bfrag[k] = *(const bf16x8*)(w2t + (nw + l15) * 128 + k * 32 + l4 * 8);

    uint4 sR[2][4], sC[2][4];
    int2 e2[2];

    e2[0] = eg[base + el];
    e2[1] = eg[base + 128 + el];
    {
        const uint4* pr = (const uint4*)(Rr + (size_t)e2[0].x * 128 + part * 32);
        const uint4* pc = (const uint4*)(Cc + (size_t)e2[0].y * 128 + part * 32);
        #pragma unroll
        for (int qq = 0; qq < 4; ++qq) { sR[0][qq] = pr[qq]; sC[0][qq] = pc[qq]; }
    }

    #pragma unroll
    for (int t = 0; t < TILES; ++t) {
        const int b = t & 1;
        unsigned short* Hc = b ? H1 : H0;
        int* rowsc = b ? rows1 : rows0;
        const int rcur = e2[b].x;

        if (t + 1 < TILES) {   // issue next tile's gathers (stay in flight)
            const uint4* pr = (const uint4*)(Rr + (size_t)e2[b ^ 1].x * 128 + part * 32);
            const uint4* pc = (const uint4*)(Cc + (size_t)e2[b ^ 1].y * 128 + part * 32);
            #pragma unroll
            for (int qq = 0; qq < 4; ++qq) { sR[b ^ 1][qq] = pr[qq]; sC[b ^ 1][qq] = pc[qq]; }
        }
        if (t + 2 < TILES) e2[b] = eg[base + (size_t)(t + 2) * 128 + el];

        // pack h = relu(R + C) into H[b]
        if (part == 0) rowsc[el] = rcur;
        {
            uint4* Hw = (uint4*)((unsigned*)Hc + el * 68 + part * 16);
            #pragma unroll
            for (int qq = 0; qq < 4; ++qq) {
                uint4 pv = sR[b][qq], qv = sC[b][qq];
                unsigned w0 = pack2(fmaxf(bflo(pv.x) + bflo(qv.x), 0.f),
                                    fmaxf(bfhi(pv.x) + bfhi(qv.x), 0.f));
                unsigned w1v = pack2(fmaxf(bflo(pv.y) + bflo(qv.y), 0.f),
                                     fmaxf(bfhi(pv.y) + bfhi(qv.y), 0.f));
                unsigned w2v = pack2(fmaxf(bflo(pv.z) + bflo(qv.z), 0.f),
                                     fmaxf(bfhi(pv.z) + bfhi(qv.z), 0.f));
                unsigned w3v = pack2(fmaxf(bflo(pv.w) + bflo(qv.w), 0.f),
                                     fmaxf(bfhi(pv.w) + bfhi(qv.w), 0.f));
                Hw[qq] = make_uint4(w0, w1v, w2v, w3v);
            }
        }
        LBARRIER();

        f32x4 acc[4];
        #pragma unroll
        for (int m = 0; m < 4; ++m) acc[m] = (f32x4){0.f, 0.f, 0.f, 0.f};
        #pragma unroll
        for (int k = 0; k < 4; ++k) {
            int kb = k * 32 + l4 * 8;
            #pragma unroll
            for (int m = 0; m < 4; ++m) {
                bf16x8 a = *(const bf16x8*)(Hc + (mh + m * 16 + l15) * 136 + kb);
                acc[m] = __builtin_amdgcn_mfma_f32_16x16x32_bf16(a, bfrag[k], acc[m], 0, 0, 0);
            }
        }
        LBARRIER();   // all H[b] reads done before S overwrite

        float* S = (float*)Hc;   // [128][68]
        #pragma unroll
        for (int m = 0; m < 4; ++m) {
            int rb = mh + m * 16 + l4 * 4;
            #pragma unroll
            for (int r = 0; r < 4; ++r)
                S[(rb + r) * 68 + nw + l15] = acc[m][r];
        }
        LBARRIER();

        {   // run-merged segment reduction: thread = (col=lane, group=wave)
            const int c = lane;
            const int e0g = wave * 16;
            float sv[16];
            #pragma unroll
            for (int r = 0; r < 16; ++r) sv[r] = S[(e0g + r) * 68 + c];
            int rw[16];
            #pragma unroll
            for (int r = 0; r < 16; ++r)
                rw[r] = __builtin_amdgcn_readfirstlane(rowsc[e0g + r]);
            int cur = rw[0];
            float v = sv[0];
            #pragma unroll
            for (int r = 1; r < 16; ++r) {
                if (rw[r] == cur) { v += sv[r]; }
                else { unsafeAtomicAdd(sumout + (size_t)cur * 64 + c, v); cur = rw[r]; v = sv[r]; }
            }
            unsafeAtomicAdd(sumout + (size_t)cur * 64 + c, v);
        }
        // next iter packs the other H buffer; its last readers finished
        // before this tile's barriers -> no extra barrier needed.
    }
}

// ---------------------------------------------------------------------------
// ctx_pq (fused): phase 1 computes ctx = MLP(mean(m1)+l1m_b2) in-register;
// phase 2 builds the PQ A-tile [128][248]bf16 directly in LDS and computes
// P/Q with B read from L2-hot global. LDS 62 KB -> 2 blocks/CU.
// ---------------------------------------------------------------------------
#define CP_LDS (128 * 248 * 2)   // 63488 B; phase-1 A1(18432)+H1(34816) fit inside

__global__ __launch_bounds__(512, 4) void ctx_pq(
    const float* __restrict__ sum1, const float* __restrict__ cnt,
    const float* __restrict__ mb2,
    const unsigned short* __restrict__ aw1t, const float* __restrict__ ab1,
    const unsigned short* __restrict__ aw2t, const float* __restrict__ ab2,
    const float* __restrict__ x, const float* __restrict__ pos,
    const unsigned short* __restrict__ wp, const unsigned short* __restrict__ wq,
    const float* __restrict__ b1,
    unsigned short* __restrict__ Pp, unsigned short* __restrict__ Qq)
{
    extern __shared__ char smem[];
    unsigned short* A1 = (unsigned short*)smem;            // [128][72]
    unsigned short* H1 = (unsigned short*)(smem + 18432);  // [128][136]
    const int tid = threadIdx.x;
    const int nb = blockIdx.x * 128;
    const int nl = tid >> 2, part = tid & 3;
    const int lane = tid & 63, l15 = lane & 15, l4 = lane >> 4;
    const int wave = tid >> 6;
    const int mh = (wave >> 2) * 64;

    int n = nb + nl; if (n >= N_NODESC) n = N_NODESC - 1;

    float4 xr[4];
    {
        const float4* xs = (const float4*)(x + (size_t)n * XD + part * 16);
        #pragma unroll
        for (int q = 0; q < 4; ++q) xr[q] = xs[q];
    }
    float2 posr = *(const float2*)(pos + 2 * (size_t)n);

    // phase 1a: A1 = bf16(mean(sum1) + mb2)
    {
        float inv = 1.0f / fmaxf(cnt[n], 1.0f);
        const float4* s = (const float4*)(sum1 + (size_t)n * CTXD + part * 16);
        const float4* m = (const float4*)(mb2 + part * 16);
        unsigned* Aw = (unsigned*)A1 + nl * 36 + part * 8;
        #pragma unroll
        for (int q = 0; q < 4; ++q) {
            float4 v = s[q]; float4 b = m[q];
            Aw[2 * q]     = pack2(fmaf(v.x, inv, b.x), fmaf(v.y, inv, b.y));
            Aw[2 * q + 1] = pack2(fmaf(v.z, inv, b.z), fmaf(v.w, inv, b.w));
        }
    }
    __syncthreads();

    // phase 1b: hidden = relu(A1 @ aw1t + ab1) -> H1
    const int nq = (wave & 3) * 32;
    {
        f32x4 acc1[4][2];
        #pragma unroll
        for (int m = 0; m < 4; ++m)
            #pragma unroll
            for (int nn = 0; nn < 2; ++nn) acc1[m][nn] = (f32x4){0.f, 0.f, 0.f, 0.f};
        #pragma unroll
        for (int kc = 0; kc < 2; ++kc) {
            int kb = kc * 32 + l4 * 8;
            bf16x8 b0 = *(const bf16x8*)(aw1t + (nq + l15) * 64 + kb);
            bf16x8 b1v = *(const bf16x8*)(aw1t + (nq + 16 + l15) * 64 + kb);
            #pragma unroll
            for (int m = 0; m < 4; ++m) {
                bf16x8 a = *(const bf16x8*)(A1 + (mh + m * 16 + l15) * 72 + kb);
                acc1[m][0] = __builtin_amdgcn_mfma_f32_16x16x32_bf16(a, b0, acc1[m][0], 0, 0, 0);
                acc1[m][1] = __builtin_amdgcn_mfma_f32_16x16x32_bf16(a, b1v, acc1[m][1], 0, 0, 0);
            }
        }
        float bv0 = ab1[nq + l15], bv1 = ab1[nq + 16 + l15];
        #pragma unroll
        for (int m = 0; m < 4; ++m) {
            int rb = mh + m * 16 + l4 * 4;
            #pragma unroll
            for (int nn = 0; nn < 2; ++nn) {
                float bv = nn ? bv1 : bv0;
                int col = nq + nn * 16 + l15;
                #pragma unroll
                for (int r = 0; r < 4; ++r)
                    H1[(rb + r) * 136 + col] = f2bf(fmaxf(acc1[m][nn][r] + bv, 0.f));
            }
        }
    }
    __syncthreads();

    // phase 1c: ctx = H1 @ aw2t + ab2 (kept in acc2 registers)
    const int nw = (wave & 3) * 16;
    f32x4 acc2[4];
    #pragma unroll
    for (int m = 0; m < 4; ++m) acc2[m] = (f32x4){0.f, 0.f, 0.f, 0.f};
    #pragma unroll
    for (int kc = 0; kc < 4; ++kc) {
        int kb = kc * 32 + l4 * 8;
        bf16x8 b = *(const bf16x8*)(aw2t + (nw + l15) * 128 + kb);
        #pragma unroll
        for (int m = 0; m < 4; ++m) {
            bf16x8 a = *(const bf16x8*)(H1 + (mh + m * 16 + l15) * 136 + kb);
            acc2[m] = __builtin_amdgcn_mfma_f32_16x16x32_bf16(a, b, acc2[m], 0, 0, 0);
        }
    }
    float cb2 = ab2[nw + l15];
    __syncthreads();   // all A1/H1 reads complete before A2 overwrites

    // phase 2a: build A2 [128 nodes][248 shorts]: x | ctx | pos | zeros
    {
        unsigned* Aw = (unsigned*)smem + nl * 124;
        #pragma unroll
        for (int q = 0; q < 4; ++q) {
            Aw[part * 8 + 2 * q]     = pack2(xr[q].x, xr[q].y);
            Aw[part * 8 + 2 * q + 1] = pack2(xr[q].z, xr[q].w);
        }
        if (part < 3) {
            #pragma unroll
            for (int z = 0; z < 15; ++z) Aw[65 + part * 15 + z] = 0u;
        } else {
            #pragma unroll
            for (int z = 0; z < 14; ++z) Aw[110 + z] = 0u;
            Aw[64] = pack2(posr.x, posr.y);   // feats 128,129
        }
    }
    {   // ctx (bf16) into feats 64..127 straight from accumulators
        unsigned short* A2s = (unsigned short*)smem;
        #pragma unroll
        for (int m = 0; m < 4; ++m) {
            int rb = mh + m * 16 + l4 * 4;
            #pragma unroll
            for (int r = 0; r < 4; ++r)
                A2s[(rb + r) * 248 + 64 + nw + l15] = f2bf(acc2[m][r] + cb2);
        }
    }
    __syncthreads();

    // phase 2b: P/Q MFMAs; B operands from L2-hot global
    const int nq2 = wave & 3;
    f32x4 acc[4][4];
    #pragma unroll
    for (int m = 0; m < 4; ++m)
        #pragma unroll
        for (int nn = 0; nn < 4; ++nn) acc[m][nn] = (f32x4){0.f, 0.f, 0.f, 0.f};

    if (nq2 < 2) {
        const int cb = nq2 * 64;
        #pragma unroll
        for (int kc = 0; kc < 7; ++kc) {
            int ks = kc * 32 + l4 * 8;        // short offset within 224-row
            int ko = ks * 2;                  // byte offset within 496-stride
            bf16x8 b0 = *(const bf16x8*)(wp + (cb + l15) * 224 + ks);
            bf16x8 b1v = *(const bf16x8*)(wp + (cb + 16 + l15) * 224 + ks);
            bf16x8 b2v = *(const bf16x8*)(wp + (cb + 32 + l15) * 224 + ks);
            bf16x8 b3v = *(const bf16x8*)(wp + (cb + 48 + l15) * 224 + ks);
            #pragma unroll
            for (int m = 0; m < 4; ++m) {
                bf16x8 a = *(const bf16x8*)(smem + (mh + m * 16 + l15) * 496 + ko);
                acc[m][0] = __builtin_amdgcn_mfma_f32_16x16x32_bf16(a, b0, acc[m][0], 0, 0, 0);
                acc[m][1] = __builtin_amdgcn_mfma_f32_16x16x32_bf16(a, b1v, acc[m][1], 0, 0, 0);
                acc[m][2] = __builtin_amdgcn_mfma_f32_16x16x32_bf16(a, b2v, acc[m][2], 0, 0, 0);
                acc[m][3] = __builtin_amdgcn_mfma_f32_16x16x32_bf16(a, b3v, acc[m][3], 0, 0, 0);
            }
        }
        #pragma unroll
        for (int nn = 0; nn < 4; ++nn) {
            int col = cb + nn * 16 + l15;
            float bb = b1[col];
            #pragma unroll
            for (int m = 0; m < 4; ++m) {
                int rb = mh + m * 16 + l4 * 4;
                #pragma unroll
                for (int r = 0; r < 4; ++r) {
                    int node = nb + rb + r;
                    if (node < N_NODESC)
                        Pp[(size_t)node * 128 + col] = f2bf(acc[m][nn][r] + bb);
                }
            }
        }
    } else {
        const int cb = (nq2 - 2) * 64;
        const int kcs[3] = {0, 1, 4};
        #pragma unroll
        for (int tk2 = 0; tk2 < 3; ++tk2) {
            int kc = kcs[tk2];
            int ks = kc * 32 + l4 * 8;
            bf16x8 b0 = *(const bf16x8*)(wq + (cb + l15) * 224 + ks);
            bf16x8 b1v = *(const bf16x8*)(wq + (cb + 16 + l15) * 224 + ks);
            bf16x8 b2v = *(const bf16x8*)(wq + (cb + 32 + l15) * 224 + ks);
            bf16x8 b3v = *(const bf16x8*)(wq + (cb + 48 + l15) * 224 + ks);
            #pragma unroll
            for (int m = 0; m < 4; ++m) {
                bf16x8 a = *(const bf16x8*)(smem + (mh + m * 16 + l15) * 496 + ks * 2);
                acc[m][0] = __builtin_amdgcn_mfma_f32_16x16x32_bf16(a, b0, acc[m][0], 0, 0, 0);
                acc[m][1] = __builtin_amdgcn_mfma_f32_16x16x32_bf16(a, b1v, acc[m][1], 0, 0, 0);
                acc[m][2] = __builtin_amdgcn_mfma_f32_16x16x32_bf16(a, b2v, acc[m][2], 0, 0, 0);
                acc[m][3] = __builtin_amdgcn_mfma_f32_16x16x32_bf16(a, b3v, acc[m][3], 0, 0, 0);
            }
        }
        #pragma unroll
        for (int nn = 0; nn < 4; ++nn) {
            int col = cb + nn * 16 + l15;
            #pragma unroll
            for (int m = 0; m < 4; ++m) {
                int rb = mh + m * 16 + l4 * 4;
                #pragma unroll
                for (int r = 0; r < 4; ++r) {
                    int node = nb + rb + r;
                    if (node < N_NODESC)
                        Qq[(size_t)node * 128 + col] = f2bf(acc[m][nn][r]);
                }
            }
        }
    }
}

// ---------------------------------------------------------------------------
// out = MLP([x, mean(m2)+l2m_b2]) (128 -> 128 -> 64), MFMA
// ---------------------------------------------------------------------------
__global__ __launch_bounds__(512) void out_mfma(
    const float* __restrict__ x, const float* __restrict__ sum2,
    const float* __restrict__ cnt, const float* __restrict__ mb2,
    const unsigned short* __restrict__ bw1t, const float* __restrict__ ab1,
    const unsigned short* __restrict__ bw2t, const float* __restrict__ ab2,
    float* __restrict__ out)
{
    extern __shared__ unsigned short sm[];
    unsigned short* A = sm;              // [128][136]
    unsigned short* H = sm + 128 * 136;  // [128][136]
    const int tid = threadIdx.x;
    const int nb = blockIdx.x * 128;

    {
        int nl = tid >> 2, part = tid & 3;
        int n = nb + nl; if (n >= N_NODESC) n = N_NODESC - 1;
        unsigned* Aw = (unsigned*)A + nl * 68 + part * 16;
        if (part < 2) {
            const float4* xs = (const float4*)(x + (size_t)n * XD + part * 32);
            #pragma unroll
            for (int q = 0; q < 8; ++q) {
                float4 v = xs[q];
                Aw[2 * q]     = pack2(v.x, v.y);
                Aw[2 * q + 1] = pack2(v.z, v.w);
            }
        } else {
            float inv = 1.0f / fmaxf(cnt[n], 1.0f);
            const float4* s = (const float4*)(sum2 + (size_t)n * OUTD + (part - 2) * 32);
            const float4* m = (const float4*)(mb2 + (part - 2) * 32);
            #pragma unroll
            for (int q = 0; q < 8; ++q) {
                float4 v = s[q]; float4 b = m[q];
                Aw[2 * q]     = pack2(fmaf(v.x, inv, b.x), fmaf(v.y, inv, b.y));
                Aw[2 * q + 1] = pack2(fmaf(v.z, inv, b.z), fmaf(v.w, inv, b.w));
            }
        }
    }
    __syncthreads();

    const int lane = tid & 63, l15 = lane & 15, l4 = lane >> 4;
    const int wave = tid >> 6;
    const int mh = (wave >> 2) * 64;
    const int nq = (wave & 3) * 32;

    f32x4 acc[4][2];
    #pragma unroll
    for (int m = 0; m < 4; ++m)
        #pragma unroll
        for (int n = 0; n < 2; ++n) acc[m][n] = (f32x4){0.f, 0.f, 0.f, 0.f};

    #pragma unroll
    for (int kc = 0; kc < 4; ++kc) {
        int kb = kc * 32 + l4 * 8;
        bf16x8 b0 = *(const bf16x8*)(bw1t + (nq + l15) * 128 + kb);
        bf16x8 b1v = *(const bf16x8*)(bw1t + (nq + 16 + l15) * 128 + kb);
        #pragma unroll
        for (int m = 0; m < 4; ++m) {
            bf16x8 a = *(const bf16x8*)(A + (mh + m * 16 + l15) * 136 + kb);
            acc[m][0] = __builtin_amdgcn_mfma_f32_16x16x32_bf16(a, b0, acc[m][0], 0, 0, 0);
            acc[m][1] = __builtin_amdgcn_mfma_f32_16x16x32_bf16(a, b1v, acc[m][1], 0, 0, 0);
        }
    }
    float bv0 = ab1[nq + l15], bv1 = ab1[nq + 16 + l15];
    #pragma unroll
    for (int m = 0; m < 4; ++m) {
        int rb = mh + m * 16 + l4 * 4;
        #pragma unroll
        for (int nn = 0; nn < 2; ++nn) {
            float bv = nn ? bv1 : bv0;
            int col = nq + nn * 16 + l15;
            #pragma unroll
            for (int r = 0; r < 4; ++r)
                H[(rb + r) * 136 + col] = f2bf(fmaxf(acc[m][nn][r] + bv, 0.f));
        }
    }
    __syncthreads();

    const int nw = (wave & 3) * 16;
    f32x4 acc2[4];
    #pragma unroll
    for (int m = 0; m < 4; ++m) acc2[m] = (f32x4){0.f, 0.f, 0.f, 0.f};
    #pragma unroll
    for (int kc = 0; kc < 4; ++kc) {
        int kb = kc * 32 + l4 * 8;
        bf16x8 b = *(const bf16x8*)(bw2t + (nw + l15) * 128 + kb);
        #pragma unroll
        for (int m = 0; m < 4; ++m) {
            bf16x8 a = *(const bf16x8*)(H + (mh + m * 16 + l15) * 136 + kb);
            acc2[m] = __builtin_amdgcn_mfma_f32_16x16x32_bf16(a, b, acc2[m], 0, 0, 0);
        }
    }
    float b2 = ab2[nw + l15];
    #pragma unroll
    for (int m = 0; m < 4; ++m) {
        int rb = mh + m * 16 + l4 * 4;
        #pragma unroll
        for (int r = 0; r < 4; ++r) {
            int node = nb + rb + r;
            if (node < N_NODESC)
                out[(size_t)node * OUTD + nw + l15] = acc2[m][r] + b2;
        }
    }
}

// ---------------------------------------------------------------------------
extern "C" void kernel_launch(void* const* d_in, const int* in_sizes, int n_in,
                              void* d_out, int out_size, void* d_ws, size_t ws_size,
                              hipStream_t stream)
{
    const float* x      = (const float*)d_in[0];
    const float* pos    = (const float*)d_in[1];
    const int*   ei     = (const int*)  d_in[2];
    const float* l1m_w1 = (const float*)d_in[3];
    const float* l1m_b1 = (const float*)d_in[4];
    const float* l1m_w2 = (const float*)d_in[5];
    const float* l1m_b2 = (const float*)d_in[6];
    const float* l1a_w1 = (const float*)d_in[7];
    const float* l1a_b1 = (const float*)d_in[8];
    const float* l1a_w2 = (const float*)d_in[9];
    const float* l1a_b2 = (const float*)d_in[10];
    const float* l2m_w1 = (const float*)d_in[11];
    const float* l2m_b1 = (const float*)d_in[12];
    const float* l2m_w2 = (const float*)d_in[13];
    const float* l2m_b2 = (const float*)d_in[14];
    const float* l2a_w1 = (const float*)d_in[15];
    const float* l2a_b1 = (const float*)d_in[16];
    const float* l2a_w2 = (const float*)d_in[17];
    const float* l2a_b2 = (const float*)d_in[18];

    float* ws    = (float*)d_ws;
    float* sum1  = ws;                                   // [N][64]
    float* sum2  = sum1 + (size_t)N_NODESC * CTXD;       // [N][64]
    float* ctxb  = sum2 + (size_t)N_NODESC * OUTD;       // [N][64] (unused hole)
    float* cnt_f = ctxb + (size_t)N_NODESC * CTXD;       // [NBINS]
    unsigned short* Pp   = (unsigned short*)(cnt_f + NBINS);    // [N][128]
    unsigned short* Qq   = Pp + (size_t)N_NODESC * 128;         // [N][128]
    unsigned short* Un   = Pp;   // L1 row-side (aliases Pp; dead before ctx_pq)
    unsigned short* U    = Qq;   // L1 col-side (aliases Qq)
    int2* eg2            = (int2*)Pp;  // bucket-scatter temp (dead before prep_node_u)
    unsigned short* wp   = Qq + (size_t)N_NODESC * 128;         // 128*224
    unsigned short* wq   = wp + 128 * 224;
    unsigned short* w2t1 = wq + 128 * 224;               // 64*128
    unsigned short* w2t2 = w2t1 + 64 * 128;
    unsigned short* aw1t = w2t2 + 64 * 128;              // 128*64
    unsigned short* aw2t = aw1t + 128 * 64;              // 64*128
    unsigned short* bw1t = aw2t + 64 * 128;              // 128*128
    unsigned short* bw2t = bw1t + 128 * 128;             // 64*128
    int* gh     = (int*)(bw2t + 64 * 128);               // [NBKT]
    int* bbase  = gh + NBKT;                             // [NBKT]
    int* bcur   = bbase + NBKT;                          // [NBKT]
    int2* eg    = (int2*)(bcur + NBKT + 2);              // [E] (8B aligned)

    hipMemsetAsync(d_ws, 0, (size_t)2 * N_NODESC * 64 * sizeof(float), stream);
    hipMemsetAsync(gh, 0, NBKT * sizeof(int), stream);

    hipFuncSetAttribute((const void*)edge_mlp,
                        hipFuncAttributeMaxDynamicSharedMemorySize, EM_LDS);
    hipFuncSetAttribute((const void*)ctx_pq,
                        hipFuncAttributeMaxDynamicSharedMemorySize, CP_LDS);
    hipFuncSetAttribute((const void*)out_mfma,
                        hipFuncAttributeMaxDynamicSharedMemorySize, 2 * 128 * 136 * 2);

    bhist_k<<<256, 256, 0, stream>>>(ei, gh);
    bscan_k<<<1, 256, 0, stream>>>(gh, bbase, bcur);
    bscat_k<<<SC_BLOCKS, 1024, 0, stream>>>(ei, bcur, eg2);
    bsort_k<<<NBKT, 1024, 0, stream>>>(eg2, bbase, gh, eg, cnt_f);

    // merged prep_weights + node_u (independent work; eg2 is dead by now)
    prep_node_u<<<PU_PREP_BLOCKS + PU_NODE_BLOCKS, 256, 0, stream>>>(
        l2m_w1, l2m_w2, l1m_w2, l1a_w1, l1a_w2, l2a_w1, l2a_w2,
        pos, l1m_w1, l1m_b1,
        wp, wq, w2t1, w2t2, aw1t, aw2t, bw1t, bw2t, U, Un);

    edge_mlp<<<N_EDGESC / (128 * TILES), 512, EM_LDS, stream>>>(
        eg, Un, U, w2t1, sum1);

    ctx_pq<<<(N_NODESC + 127) / 128, 512, CP_LDS, stream>>>(
        sum1, cnt_f, l1m_b2, aw1t, l1a_b1, aw2t, l1a_b2,
        x, pos, wp, wq, l2m_b1, Pp, Qq);

    edge_mlp<<<N_EDGESC / (128 * TILES), 512, EM_LDS, stream>>>(
        eg, Pp, Qq, w2t2, sum2);

    out_mfma<<<(N_NODESC + 127) / 128, 512, 2 * 128 * 136 * 2, stream>>>(
        x, sum2, cnt_f, l2m_b2, bw1t, l2a_b1, bw2t, l2a_b2, (float*)d_out);
}